// Round 1
// baseline (835.181 us; speedup 1.0000x reference)
//
#include <hip/hip_runtime.h>
#include <stdint.h>

#define N_NODES 10000
#define F_IN    512
#define E_DIM   256
#define H0D     512
#define H1D     256
#define N_EDGES 160000
#define T_TOT   (N_EDGES + N_NODES)   // 170000

#define MT 64
#define KB 32

// monotone map fp32 -> uint32 (order-preserving)
__device__ __forceinline__ unsigned int f2ord(float f) {
    unsigned int u = __float_as_uint(f);
    return (u & 0x80000000u) ? ~u : (u | 0x80000000u);
}

// ---------------------------------------------------------------------------
// K1: Z = feature @ We + be  (pre-relu, cached);  out = relu(Z)  (= emb)
// M=10000, K=512, N=256. Tile 64x256, Kblk=32, 256 threads.
// ---------------------------------------------------------------------------
__global__ __launch_bounds__(256, 2) void k1_emb(
        const float* __restrict__ feat, const float* __restrict__ We,
        const float* __restrict__ be, float* __restrict__ Z,
        float* __restrict__ out) {
    __shared__ float Al[MT][KB + 4];
    __shared__ float Bl[KB][256];
    const int tid = threadIdx.x;
    const int rg = tid >> 5, cg = tid & 31;
    const int mbase = blockIdx.x * MT;
    float acc[8][8];
#pragma unroll
    for (int i = 0; i < 8; i++)
#pragma unroll
        for (int j = 0; j < 8; j++) acc[i][j] = 0.f;

    for (int k0 = 0; k0 < F_IN; k0 += KB) {
#pragma unroll
        for (int r = 0; r < 2; r++) {
            int f = tid + 256 * r;
            int m = f >> 3, q = f & 7;
            int gm = mbase + m;
            float4 v = make_float4(0.f, 0.f, 0.f, 0.f);
            if (gm < N_NODES)
                v = *(const float4*)(feat + (size_t)gm * F_IN + k0 + q * 4);
            *(float4*)(&Al[m][q * 4]) = v;
        }
#pragma unroll
        for (int r = 0; r < 8; r++) {
            int f = tid + 256 * r;
            int kk = f >> 6, q = f & 63;
            *(float4*)(&Bl[kk][q * 4]) =
                *(const float4*)(We + (size_t)(k0 + kk) * E_DIM + q * 4);
        }
        __syncthreads();
        for (int kk = 0; kk < KB; kk++) {
            float a[8], b[8];
#pragma unroll
            for (int i = 0; i < 8; i++) a[i] = Al[rg * 8 + i][kk];
#pragma unroll
            for (int j = 0; j < 8; j++) b[j] = Bl[kk][cg + 32 * j];
#pragma unroll
            for (int i = 0; i < 8; i++)
#pragma unroll
                for (int j = 0; j < 8; j++) acc[i][j] = fmaf(a[i], b[j], acc[i][j]);
        }
        __syncthreads();
    }
#pragma unroll
    for (int i = 0; i < 8; i++) {
        int gm = mbase + rg * 8 + i;
        if (gm >= N_NODES) continue;
#pragma unroll
        for (int j = 0; j < 8; j++) {
            int n = cg + 32 * j;
            float z = acc[i][j] + be[n];
            Z[(size_t)gm * E_DIM + n] = z;
            out[(size_t)gm * E_DIM + n] = fmaxf(z, 0.f);
        }
    }
}

// ---------------------------------------------------------------------------
// K2: P' = emb @ W0[0:256,:] + b0   (10000 x 512)
//     Q  = emb @ W0[256:512,:]      (10000 x 512)
// One virtual GEMM [10000,256] @ [256,1024]; blockIdx.y selects 256-col chunk.
// ---------------------------------------------------------------------------
__global__ __launch_bounds__(256, 2) void k2_pq(
        const float* __restrict__ emb, const float* __restrict__ W0,
        const float* __restrict__ b0, float* __restrict__ P,
        float* __restrict__ Qm) {
    __shared__ float Al[MT][KB + 4];
    __shared__ float Bl[KB][256];
    const int tid = threadIdx.x;
    const int rg = tid >> 5, cg = tid & 31;
    const int mbase = blockIdx.x * MT;
    const int isQ = (blockIdx.y >= 2);
    const int colbase = (blockIdx.y & 1) * 256;
    const int rowoff = isQ ? 256 : 0;
    float acc[8][8];
#pragma unroll
    for (int i = 0; i < 8; i++)
#pragma unroll
        for (int j = 0; j < 8; j++) acc[i][j] = 0.f;

    for (int k0 = 0; k0 < E_DIM; k0 += KB) {
#pragma unroll
        for (int r = 0; r < 2; r++) {
            int f = tid + 256 * r;
            int m = f >> 3, q = f & 7;
            int gm = mbase + m;
            float4 v = make_float4(0.f, 0.f, 0.f, 0.f);
            if (gm < N_NODES)
                v = *(const float4*)(emb + (size_t)gm * E_DIM + k0 + q * 4);
            *(float4*)(&Al[m][q * 4]) = v;
        }
#pragma unroll
        for (int r = 0; r < 8; r++) {
            int f = tid + 256 * r;
            int kk = f >> 6, q = f & 63;
            *(float4*)(&Bl[kk][q * 4]) = *(const float4*)(
                W0 + (size_t)(rowoff + k0 + kk) * H0D + colbase + q * 4);
        }
        __syncthreads();
        for (int kk = 0; kk < KB; kk++) {
            float a[8], b[8];
#pragma unroll
            for (int i = 0; i < 8; i++) a[i] = Al[rg * 8 + i][kk];
#pragma unroll
            for (int j = 0; j < 8; j++) b[j] = Bl[kk][cg + 32 * j];
#pragma unroll
            for (int i = 0; i < 8; i++)
#pragma unroll
                for (int j = 0; j < 8; j++) acc[i][j] = fmaf(a[i], b[j], acc[i][j]);
        }
        __syncthreads();
    }
    float* dst = isQ ? Qm : P;
#pragma unroll
    for (int i = 0; i < 8; i++) {
        int gm = mbase + rg * 8 + i;
        if (gm >= N_NODES) continue;
#pragma unroll
        for (int j = 0; j < 8; j++) {
            int n = cg + 32 * j;
            float v = acc[i][j];
            if (!isQ) v += b0[colbase + n];
            dst[(size_t)gm * H0D + colbase + n] = v;
        }
    }
}

// ---------------------------------------------------------------------------
// K3 (dominant): per entry t: h1 = relu(P'[seg] + Q[dst]);  h = relu(h1@W1+b1)
//   lk = h.Wlk + blk ; logits = h.Wa + ba
//   atomicMax packed (lk, t) per segment; store logits.
// GEMM [T,512]@[512,256], A gathered on the fly. Tile 64x256, Kblk=32.
// ---------------------------------------------------------------------------
__global__ __launch_bounds__(256, 2) void k3_edge(
        const float* __restrict__ P, const float* __restrict__ Qm,
        const float* __restrict__ W1, const float* __restrict__ b1,
        const float* __restrict__ Wlk, const float* __restrict__ blkp,
        const float* __restrict__ Wa, const float* __restrict__ ba,
        const int* __restrict__ esrc, const int* __restrict__ edst,
        unsigned long long* __restrict__ keys, float* __restrict__ logits) {
    __shared__ float Al[MT][KB + 4];
    __shared__ float Bl[KB][256];
    __shared__ int s_seg[MT];
    __shared__ int s_dst[MT];
    const int tid = threadIdx.x;
    const int rg = tid >> 5, cg = tid & 31;
    const int tbase = blockIdx.x * MT;

    if (tid < MT) {
        int t = tbase + tid;
        int s = 0, d = -1;
        if (t < N_EDGES) { s = esrc[t]; d = edst[t]; }
        else if (t < T_TOT) { s = t - N_EDGES; d = -1; }
        s_seg[tid] = s;
        s_dst[tid] = d;
    }
    __syncthreads();

    float acc[8][8];
#pragma unroll
    for (int i = 0; i < 8; i++)
#pragma unroll
        for (int j = 0; j < 8; j++) acc[i][j] = 0.f;

    for (int k0 = 0; k0 < H0D; k0 += KB) {
#pragma unroll
        for (int r = 0; r < 2; r++) {
            int f = tid + 256 * r;
            int m = f >> 3, q = f & 7;
            int s = s_seg[m], d = s_dst[m];
            float4 v = *(const float4*)(P + (size_t)s * H0D + k0 + q * 4);
            if (d >= 0) {
                float4 w = *(const float4*)(Qm + (size_t)d * H0D + k0 + q * 4);
                v.x += w.x; v.y += w.y; v.z += w.z; v.w += w.w;
            }
            v.x = fmaxf(v.x, 0.f); v.y = fmaxf(v.y, 0.f);
            v.z = fmaxf(v.z, 0.f); v.w = fmaxf(v.w, 0.f);
            *(float4*)(&Al[m][q * 4]) = v;
        }
#pragma unroll
        for (int r = 0; r < 8; r++) {
            int f = tid + 256 * r;
            int kk = f >> 6, q = f & 63;
            *(float4*)(&Bl[kk][q * 4]) =
                *(const float4*)(W1 + (size_t)(k0 + kk) * H1D + q * 4);
        }
        __syncthreads();
        for (int kk = 0; kk < KB; kk++) {
            float a[8], b[8];
#pragma unroll
            for (int i = 0; i < 8; i++) a[i] = Al[rg * 8 + i][kk];
#pragma unroll
            for (int j = 0; j < 8; j++) b[j] = Bl[kk][cg + 32 * j];
#pragma unroll
            for (int i = 0; i < 8; i++)
#pragma unroll
                for (int j = 0; j < 8; j++) acc[i][j] = fmaf(a[i], b[j], acc[i][j]);
        }
        __syncthreads();
    }

    // epilogue: h = relu(acc + b1), then the three 256-dot heads
    float wl[8], wa0[8], wa1[8], bb1[8];
#pragma unroll
    for (int j = 0; j < 8; j++) {
        int n = cg + 32 * j;
        wl[j] = Wlk[n];
        wa0[j] = Wa[2 * n];
        wa1[j] = Wa[2 * n + 1];
        bb1[j] = b1[n];
    }
#pragma unroll
    for (int i = 0; i < 8; i++) {
        float plk = 0.f, p0 = 0.f, p1 = 0.f;
#pragma unroll
        for (int j = 0; j < 8; j++) {
            float h = fmaxf(acc[i][j] + bb1[j], 0.f);
            plk = fmaf(h, wl[j], plk);
            p0 = fmaf(h, wa0[j], p0);
            p1 = fmaf(h, wa1[j], p1);
        }
        // reduce across the 32 cg lanes (stays within each 32-lane half)
#pragma unroll
        for (int off = 16; off >= 1; off >>= 1) {
            plk += __shfl_xor(plk, off);
            p0 += __shfl_xor(p0, off);
            p1 += __shfl_xor(p1, off);
        }
        if (cg == 0) {
            int m = rg * 8 + i;
            int t = tbase + m;
            if (t < T_TOT) {
                float lk = plk + blkp[0];
                logits[2 * t] = p0 + ba[0];
                logits[2 * t + 1] = p1 + ba[1];
                unsigned long long key =
                    ((unsigned long long)f2ord(lk) << 32) | (unsigned int)t;
                atomicMax(keys + s_seg[m], key);
            }
        }
    }
}

// ---------------------------------------------------------------------------
// K4: per node: winner entry = low 32 bits of key (max lk, tie -> max t).
// chosen = dst of winner; at = argmax(logits[win]); do_upd; last-writer claim.
// ---------------------------------------------------------------------------
__global__ void k4_select(const unsigned long long* __restrict__ keys,
                          const int* __restrict__ edst,
                          const float* __restrict__ logits,
                          int* __restrict__ chosen_arr,
                          int* __restrict__ tgt_writer) {
    int i = blockIdx.x * 256 + threadIdx.x;
    if (i >= N_NODES) return;
    unsigned long long key = keys[i];
    int t = (int)(key & 0xFFFFFFFFull);
    int chosen = (t < N_EDGES) ? edst[t] : -1;
    float lg0 = logits[2 * t], lg1 = logits[2 * t + 1];
    int at1 = (lg1 > lg0) ? 1 : 0;   // argmax: tie -> index 0
    int c = (chosen >= 0 && at1) ? chosen : -1;
    chosen_arr[i] = c;
    if (c >= 0) atomicMax(tgt_writer + c, i);   // numpy last-write-wins: max i
}

// ---------------------------------------------------------------------------
// K5: winning writers update rows: out[c] = relu(0.5*(Z[i] + Z[c]))
// ---------------------------------------------------------------------------
__global__ void k5_update(const int* __restrict__ chosen_arr,
                          const int* __restrict__ tgt_writer,
                          const float* __restrict__ Z,
                          float* __restrict__ out) {
    int i = blockIdx.x;
    int c = chosen_arr[i];
    if (c < 0 || tgt_writer[c] != i) return;
    int n = threadIdx.x;
    float z = 0.5f * (Z[(size_t)i * E_DIM + n] + Z[(size_t)c * E_DIM + n]);
    out[(size_t)c * E_DIM + n] = fmaxf(z, 0.f);
}

// ---------------------------------------------------------------------------
extern "C" void kernel_launch(void* const* d_in, const int* in_sizes, int n_in,
                              void* d_out, int out_size, void* d_ws,
                              size_t ws_size, hipStream_t stream) {
    const float* feat = (const float*)d_in[0];
    const float* We   = (const float*)d_in[1];
    const float* be   = (const float*)d_in[2];
    const float* W0   = (const float*)d_in[3];
    const float* b0   = (const float*)d_in[4];
    const float* W1   = (const float*)d_in[5];
    const float* b1   = (const float*)d_in[6];
    const float* Wlk  = (const float*)d_in[7];
    const float* blkp = (const float*)d_in[8];
    const float* Wa   = (const float*)d_in[9];
    const float* ba   = (const float*)d_in[10];
    const int* esrc   = (const int*)d_in[11];
    const int* edst   = (const int*)d_in[12];
    float* out = (float*)d_out;

    char* ws = (char*)d_ws;
    float* Z  = (float*)(ws);                              // 10,240,000 B
    float* P  = (float*)(ws + 10240000);                   // 20,480,000 B
    float* Qm = (float*)(ws + 30720000);                   // 20,480,000 B
    unsigned long long* keys = (unsigned long long*)(ws + 51200000);  // 80,000 B
    float* logits = (float*)(ws + 51280000);               // 1,360,000 B
    int* chosen_arr = (int*)(ws + 52640000);               // 40,000 B
    int* tgt_writer = (int*)(ws + 52680000);               // 40,000 B

    hipMemsetAsync(keys, 0, N_NODES * sizeof(unsigned long long), stream);
    hipMemsetAsync(tgt_writer, 0xFF, N_NODES * sizeof(int), stream);

    k1_emb<<<dim3((N_NODES + MT - 1) / MT), 256, 0, stream>>>(feat, We, be, Z, out);
    k2_pq<<<dim3((N_NODES + MT - 1) / MT, 4), 256, 0, stream>>>(out, W0, b0, P, Qm);
    k3_edge<<<dim3((T_TOT + MT - 1) / MT), 256, 0, stream>>>(
        P, Qm, W1, b1, Wlk, blkp, Wa, ba, esrc, edst, keys, logits);
    k4_select<<<dim3((N_NODES + 255) / 256), 256, 0, stream>>>(
        keys, edst, logits, chosen_arr, tgt_writer);
    k5_update<<<dim3(N_NODES), 256, 0, stream>>>(chosen_arr, tgt_writer, Z, out);
}

// Round 2
// 499.346 us; speedup vs baseline: 1.6725x; 1.6725x over previous
//
#include <hip/hip_runtime.h>
#include <stdint.h>

#define N_NODES 10000
#define F_IN    512
#define E_DIM   256
#define H0D     512
#define H1D     256
#define N_EDGES 160000
#define T_TOT   (N_EDGES + N_NODES)   // 170000

#define MT 64
#define KB 32
#define FIX_BLOCKS 256
#define MARGIN 0.02f

typedef _Float16 f16;
typedef __attribute__((ext_vector_type(8))) _Float16 f16x8;
typedef __attribute__((ext_vector_type(4))) float f32x4;

// monotone map fp32 -> uint32 (order-preserving)
__device__ __forceinline__ unsigned int f2ord(float f) {
    unsigned int u = __float_as_uint(f);
    return (u & 0x80000000u) ? ~u : (u | 0x80000000u);
}
__device__ __forceinline__ float ord2f(unsigned int o) {
    unsigned int u = (o & 0x80000000u) ? (o & 0x7fffffffu) : ~o;
    return __uint_as_float(u);
}

// ---------------------------------------------------------------------------
// K1: Z = feature @ We + be  (pre-relu, cached);  out = relu(Z)  (= emb)
// fp32 exact (feeds output rows and the exact chain).
// ---------------------------------------------------------------------------
__global__ __launch_bounds__(256, 2) void k1_emb(
        const float* __restrict__ feat, const float* __restrict__ We,
        const float* __restrict__ be, float* __restrict__ Z,
        float* __restrict__ out) {
    __shared__ float Al[MT][KB + 4];
    __shared__ float Bl[KB][256];
    const int tid = threadIdx.x;
    const int rg = tid >> 5, cg = tid & 31;
    const int mbase = blockIdx.x * MT;
    float acc[8][8];
#pragma unroll
    for (int i = 0; i < 8; i++)
#pragma unroll
        for (int j = 0; j < 8; j++) acc[i][j] = 0.f;

    for (int k0 = 0; k0 < F_IN; k0 += KB) {
#pragma unroll
        for (int r = 0; r < 2; r++) {
            int f = tid + 256 * r;
            int m = f >> 3, q = f & 7;
            int gm = mbase + m;
            float4 v = make_float4(0.f, 0.f, 0.f, 0.f);
            if (gm < N_NODES)
                v = *(const float4*)(feat + (size_t)gm * F_IN + k0 + q * 4);
            *(float4*)(&Al[m][q * 4]) = v;
        }
#pragma unroll
        for (int r = 0; r < 8; r++) {
            int f = tid + 256 * r;
            int kk = f >> 6, q = f & 63;
            *(float4*)(&Bl[kk][q * 4]) =
                *(const float4*)(We + (size_t)(k0 + kk) * E_DIM + q * 4);
        }
        __syncthreads();
        for (int kk = 0; kk < KB; kk++) {
            float a[8], b[8];
#pragma unroll
            for (int i = 0; i < 8; i++) a[i] = Al[rg * 8 + i][kk];
#pragma unroll
            for (int j = 0; j < 8; j++) b[j] = Bl[kk][cg + 32 * j];
#pragma unroll
            for (int i = 0; i < 8; i++)
#pragma unroll
                for (int j = 0; j < 8; j++) acc[i][j] = fmaf(a[i], b[j], acc[i][j]);
        }
        __syncthreads();
    }
#pragma unroll
    for (int i = 0; i < 8; i++) {
        int gm = mbase + rg * 8 + i;
        if (gm >= N_NODES) continue;
#pragma unroll
        for (int j = 0; j < 8; j++) {
            int n = cg + 32 * j;
            float z = acc[i][j] + be[n];
            Z[(size_t)gm * E_DIM + n] = z;
            out[(size_t)gm * E_DIM + n] = fmaxf(z, 0.f);
        }
    }
}

// ---------------------------------------------------------------------------
// K2: P' = emb @ W0[0:256,:] + b0 ; Q = emb @ W0[256:512,:]  (fp32 exact)
// ---------------------------------------------------------------------------
__global__ __launch_bounds__(256, 2) void k2_pq(
        const float* __restrict__ emb, const float* __restrict__ W0,
        const float* __restrict__ b0, float* __restrict__ P,
        float* __restrict__ Qm) {
    __shared__ float Al[MT][KB + 4];
    __shared__ float Bl[KB][256];
    const int tid = threadIdx.x;
    const int rg = tid >> 5, cg = tid & 31;
    const int mbase = blockIdx.x * MT;
    const int isQ = (blockIdx.y >= 2);
    const int colbase = (blockIdx.y & 1) * 256;
    const int rowoff = isQ ? 256 : 0;
    float acc[8][8];
#pragma unroll
    for (int i = 0; i < 8; i++)
#pragma unroll
        for (int j = 0; j < 8; j++) acc[i][j] = 0.f;

    for (int k0 = 0; k0 < E_DIM; k0 += KB) {
#pragma unroll
        for (int r = 0; r < 2; r++) {
            int f = tid + 256 * r;
            int m = f >> 3, q = f & 7;
            int gm = mbase + m;
            float4 v = make_float4(0.f, 0.f, 0.f, 0.f);
            if (gm < N_NODES)
                v = *(const float4*)(emb + (size_t)gm * E_DIM + k0 + q * 4);
            *(float4*)(&Al[m][q * 4]) = v;
        }
#pragma unroll
        for (int r = 0; r < 8; r++) {
            int f = tid + 256 * r;
            int kk = f >> 6, q = f & 63;
            *(float4*)(&Bl[kk][q * 4]) = *(const float4*)(
                W0 + (size_t)(rowoff + k0 + kk) * H0D + colbase + q * 4);
        }
        __syncthreads();
        for (int kk = 0; kk < KB; kk++) {
            float a[8], b[8];
#pragma unroll
            for (int i = 0; i < 8; i++) a[i] = Al[rg * 8 + i][kk];
#pragma unroll
            for (int j = 0; j < 8; j++) b[j] = Bl[kk][cg + 32 * j];
#pragma unroll
            for (int i = 0; i < 8; i++)
#pragma unroll
                for (int j = 0; j < 8; j++) acc[i][j] = fmaf(a[i], b[j], acc[i][j]);
        }
        __syncthreads();
    }
    float* dst = isQ ? Qm : P;
#pragma unroll
    for (int i = 0; i < 8; i++) {
        int gm = mbase + rg * 8 + i;
        if (gm >= N_NODES) continue;
#pragma unroll
        for (int j = 0; j < 8; j++) {
            int n = cg + 32 * j;
            float v = acc[i][j];
            if (!isQ) v += b0[colbase + n];
            dst[(size_t)gm * H0D + colbase + n] = v;
        }
    }
}

// ---------------------------------------------------------------------------
// K_PREP: W1 [512][256] fp32 -> chunked n-major f16 image
//   W1C[c][n][kk] = f16(W1[c*32+kk][n]),  c=0..15, n=0..255, kk=0..31
// Each chunk is exactly the 16KB LDS image k3_mfma stages per K-step.
// ---------------------------------------------------------------------------
__global__ void k_prep(const float* __restrict__ W1, f16* __restrict__ W1C) {
    int c = blockIdx.x;          // 16 blocks
    int n = threadIdx.x;         // 256 threads
    f16* dst = W1C + ((size_t)c * 256 + n) * 32;
    const float* src = W1 + (size_t)(c * 32) * H1D + n;
#pragma unroll
    for (int kk = 0; kk < 32; kk++) dst[kk] = (f16)src[kk * H1D];
}

// ---------------------------------------------------------------------------
// K3_MFMA (approx pass): lk for all T entries via f16 MFMA.
// A[t] = relu(P[seg]+Q[dst]) gathered+converted on the fly; B = W1C from LDS.
// Tile: 64 rows x 256 cols, 4 waves, wave tile 64x64 = 4x4 MFMA 16x16x32.
// Outputs: lk_app[t], per-segment packed (lk,t) atomicMax into keys.
// ---------------------------------------------------------------------------
__global__ __launch_bounds__(256, 2) void k3_mfma(
        const float* __restrict__ P, const float* __restrict__ Qm,
        const f16* __restrict__ W1C, const float* __restrict__ b1,
        const float* __restrict__ Wlk, const float* __restrict__ blkp,
        const int* __restrict__ esrc, const int* __restrict__ edst,
        unsigned long long* __restrict__ keys, float* __restrict__ lk_app) {
    __shared__ f16 Al[64 * 32];       // [row][kk], 4KB
    __shared__ f16 Bl[256 * 32];      // [n][kk],  16KB
    __shared__ float red[64][5];
    __shared__ int s_seg[64], s_dst[64];
    const int tid = threadIdx.x;
    const int wave = tid >> 6, lane = tid & 63;
    const int quad = lane >> 4, l15 = lane & 15;
    const int tbase = blockIdx.x * 64;

    if (tid < 64) {
        int t = tbase + tid;
        int s = 0, d = -1;
        if (t < N_EDGES) { s = esrc[t]; d = edst[t]; }
        else if (t < T_TOT) { s = t - N_EDGES; }
        s_seg[tid] = s;
        s_dst[tid] = d;
    }
    __syncthreads();

    const int arow = tid >> 2, akp = tid & 3;   // A staging: 4 threads/row
    const int sA = s_seg[arow], dA = s_dst[arow];
    const float* Prow = P + (size_t)sA * H0D + akp * 8;
    const float* Qrow = Qm + (size_t)(dA >= 0 ? dA : 0) * H0D + akp * 8;
    const bool hasQ = (dA >= 0);

    f32x4 acc[4][4];
#pragma unroll
    for (int i = 0; i < 4; i++)
#pragma unroll
        for (int j = 0; j < 4; j++) acc[i][j] = (f32x4){0.f, 0.f, 0.f, 0.f};

    for (int k0 = 0; k0 < H0D; k0 += 32) {
        // --- load + compute A fragment bytes (8 fp32 -> 8 f16 per thread) ---
        float4 a0 = *(const float4*)(Prow + k0);
        float4 a1 = *(const float4*)(Prow + k0 + 4);
        if (hasQ) {
            float4 q0 = *(const float4*)(Qrow + k0);
            float4 q1 = *(const float4*)(Qrow + k0 + 4);
            a0.x += q0.x; a0.y += q0.y; a0.z += q0.z; a0.w += q0.w;
            a1.x += q1.x; a1.y += q1.y; a1.z += q1.z; a1.w += q1.w;
        }
        f16x8 hv;
        hv[0] = (f16)fmaxf(a0.x, 0.f); hv[1] = (f16)fmaxf(a0.y, 0.f);
        hv[2] = (f16)fmaxf(a0.z, 0.f); hv[3] = (f16)fmaxf(a0.w, 0.f);
        hv[4] = (f16)fmaxf(a1.x, 0.f); hv[5] = (f16)fmaxf(a1.y, 0.f);
        hv[6] = (f16)fmaxf(a1.z, 0.f); hv[7] = (f16)fmaxf(a1.w, 0.f);
        // --- load B chunk (straight contiguous 16KB copy) ---
        const f16* bsrc = W1C + (size_t)(k0 >> 5) * (256 * 32);
        f16x8 bv[4];
#pragma unroll
        for (int r = 0; r < 4; r++)
            bv[r] = *(const f16x8*)(bsrc + (size_t)(tid + 256 * r) * 8);

        *(f16x8*)(Al + arow * 32 + akp * 8) = hv;
#pragma unroll
        for (int r = 0; r < 4; r++)
            *(f16x8*)(Bl + (size_t)(tid + 256 * r) * 8) = bv[r];
        __syncthreads();

        f16x8 af[4], bf[4];
#pragma unroll
        for (int rt = 0; rt < 4; rt++)
            af[rt] = *(const f16x8*)(Al + (rt * 16 + l15) * 32 + quad * 8);
#pragma unroll
        for (int ct = 0; ct < 4; ct++)
            bf[ct] = *(const f16x8*)(Bl + (wave * 64 + ct * 16 + l15) * 32 + quad * 8);
#pragma unroll
        for (int rt = 0; rt < 4; rt++)
#pragma unroll
            for (int ct = 0; ct < 4; ct++)
                acc[rt][ct] = __builtin_amdgcn_mfma_f32_16x16x32_f16(
                    af[rt], bf[ct], acc[rt][ct], 0, 0, 0);
        __syncthreads();
    }

    // epilogue: reduce acc -> lk per row.  C/D: col=l15, row=quad*4+reg.
    float wl[4], bb[4];
#pragma unroll
    for (int ct = 0; ct < 4; ct++) {
        int n = wave * 64 + ct * 16 + l15;
        wl[ct] = Wlk[n];
        bb[ct] = b1[n];
    }
#pragma unroll
    for (int rt = 0; rt < 4; rt++) {
#pragma unroll
        for (int reg = 0; reg < 4; reg++) {
            float p = 0.f;
#pragma unroll
            for (int ct = 0; ct < 4; ct++) {
                float h = fmaxf(acc[rt][ct][reg] + bb[ct], 0.f);
                p = fmaf(h, wl[ct], p);
            }
            p += __shfl_xor(p, 1); p += __shfl_xor(p, 2);
            p += __shfl_xor(p, 4); p += __shfl_xor(p, 8);
            if (l15 == 0) red[rt * 16 + quad * 4 + reg][wave] = p;
        }
    }
    __syncthreads();
    if (tid < 64) {
        int t = tbase + tid;
        if (t < T_TOT) {
            float lk = red[tid][0] + red[tid][1] + red[tid][2] + red[tid][3] + blkp[0];
            lk_app[t] = lk;
            unsigned long long key =
                ((unsigned long long)f2ord(lk) << 32) | (unsigned int)t;
            atomicMax(keys + s_seg[tid], key);
        }
    }
}

// ---------------------------------------------------------------------------
// K_GATHER: collect marginal candidates (within MARGIN of approx seg best).
// True winner provably included (|f16 err| << MARGIN/2).
// ---------------------------------------------------------------------------
__global__ void k_gather(const float* __restrict__ lk_app,
                         const unsigned long long* __restrict__ keys,
                         const int* __restrict__ esrc,
                         int* __restrict__ list, int* __restrict__ count) {
    int t = blockIdx.x * 256 + threadIdx.x;
    if (t >= T_TOT) return;
    int seg = (t < N_EDGES) ? esrc[t] : t - N_EDGES;
    float best = ord2f((unsigned int)(keys[seg] >> 32));
    if (lk_app[t] >= best - MARGIN) {
        int idx = atomicAdd(count, 1);
        list[idx] = t;
    }
}

// ---------------------------------------------------------------------------
// K_FIXUP: exact fp32 recompute of lk + logits for the marginal list.
// Round-1 tile structure with list indirection; grid-stride over chunks.
// ---------------------------------------------------------------------------
__global__ __launch_bounds__(256, 2) void k_fixup(
        const float* __restrict__ P, const float* __restrict__ Qm,
        const float* __restrict__ W1, const float* __restrict__ b1,
        const float* __restrict__ Wlk, const float* __restrict__ blkp,
        const float* __restrict__ Wa, const float* __restrict__ ba,
        const int* __restrict__ esrc, const int* __restrict__ edst,
        const int* __restrict__ list, const int* __restrict__ count,
        unsigned long long* __restrict__ keys2, float* __restrict__ logits) {
    __shared__ float Al[MT][KB + 4];
    __shared__ float Bl[KB][256];
    __shared__ int s_seg[MT];
    __shared__ int s_dst[MT];
    __shared__ int s_t[MT];
    const int tid = threadIdx.x;
    const int rg = tid >> 5, cg = tid & 31;
    const int cnt = *count;
    const int nch = (cnt + MT - 1) / MT;

    for (int ch = blockIdx.x; ch < nch; ch += gridDim.x) {
        if (tid < MT) {
            int li = ch * MT + tid;
            int t = (li < cnt) ? list[li] : -1;
            int s = 0, d = -1;
            if (t >= 0) {
                if (t < N_EDGES) { s = esrc[t]; d = edst[t]; }
                else { s = t - N_EDGES; }
            }
            s_t[tid] = t;
            s_seg[tid] = s;
            s_dst[tid] = d;
        }
        __syncthreads();

        float acc[8][8];
#pragma unroll
        for (int i = 0; i < 8; i++)
#pragma unroll
            for (int j = 0; j < 8; j++) acc[i][j] = 0.f;

        for (int k0 = 0; k0 < H0D; k0 += KB) {
#pragma unroll
            for (int r = 0; r < 2; r++) {
                int f = tid + 256 * r;
                int m = f >> 3, q = f & 7;
                int s = s_seg[m], d = s_dst[m];
                float4 v = *(const float4*)(P + (size_t)s * H0D + k0 + q * 4);
                if (d >= 0) {
                    float4 w = *(const float4*)(Qm + (size_t)d * H0D + k0 + q * 4);
                    v.x += w.x; v.y += w.y; v.z += w.z; v.w += w.w;
                }
                v.x = fmaxf(v.x, 0.f); v.y = fmaxf(v.y, 0.f);
                v.z = fmaxf(v.z, 0.f); v.w = fmaxf(v.w, 0.f);
                *(float4*)(&Al[m][q * 4]) = v;
            }
#pragma unroll
            for (int r = 0; r < 8; r++) {
                int f = tid + 256 * r;
                int kk = f >> 6, q = f & 63;
                *(float4*)(&Bl[kk][q * 4]) =
                    *(const float4*)(W1 + (size_t)(k0 + kk) * H1D + q * 4);
            }
            __syncthreads();
            for (int kk = 0; kk < KB; kk++) {
                float a[8], b[8];
#pragma unroll
                for (int i = 0; i < 8; i++) a[i] = Al[rg * 8 + i][kk];
#pragma unroll
                for (int j = 0; j < 8; j++) b[j] = Bl[kk][cg + 32 * j];
#pragma unroll
                for (int i = 0; i < 8; i++)
#pragma unroll
                    for (int j = 0; j < 8; j++)
                        acc[i][j] = fmaf(a[i], b[j], acc[i][j]);
            }
            __syncthreads();
        }

        float wl[8], wa0[8], wa1[8], bb1[8];
#pragma unroll
        for (int j = 0; j < 8; j++) {
            int n = cg + 32 * j;
            wl[j] = Wlk[n];
            wa0[j] = Wa[2 * n];
            wa1[j] = Wa[2 * n + 1];
            bb1[j] = b1[n];
        }
#pragma unroll
        for (int i = 0; i < 8; i++) {
            float plk = 0.f, p0 = 0.f, p1 = 0.f;
#pragma unroll
            for (int j = 0; j < 8; j++) {
                float h = fmaxf(acc[i][j] + bb1[j], 0.f);
                plk = fmaf(h, wl[j], plk);
                p0 = fmaf(h, wa0[j], p0);
                p1 = fmaf(h, wa1[j], p1);
            }
#pragma unroll
            for (int off = 16; off >= 1; off >>= 1) {
                plk += __shfl_xor(plk, off);
                p0 += __shfl_xor(p0, off);
                p1 += __shfl_xor(p1, off);
            }
            if (cg == 0) {
                int m = rg * 8 + i;
                int t = s_t[m];
                if (t >= 0) {
                    float lk = plk + blkp[0];
                    logits[2 * t] = p0 + ba[0];
                    logits[2 * t + 1] = p1 + ba[1];
                    unsigned long long key =
                        ((unsigned long long)f2ord(lk) << 32) | (unsigned int)t;
                    atomicMax(keys2 + s_seg[m], key);
                }
            }
        }
        __syncthreads();   // protect s_* before next iteration's restage
    }
}

// ---------------------------------------------------------------------------
// K4: exact winner per node from keys2; at-bit from exact logits; claim target.
// ---------------------------------------------------------------------------
__global__ void k4_select(const unsigned long long* __restrict__ keys2,
                          const int* __restrict__ edst,
                          const float* __restrict__ logits,
                          int* __restrict__ chosen_arr,
                          int* __restrict__ tgt_writer) {
    int i = blockIdx.x * 256 + threadIdx.x;
    if (i >= N_NODES) return;
    unsigned long long key = keys2[i];
    int t = (int)(key & 0xFFFFFFFFull);
    int chosen = (t < N_EDGES) ? edst[t] : -1;
    float lg0 = logits[2 * t], lg1 = logits[2 * t + 1];
    int at1 = (lg1 > lg0) ? 1 : 0;   // argmax: tie -> index 0
    int c = (chosen >= 0 && at1) ? chosen : -1;
    chosen_arr[i] = c;
    if (c >= 0) atomicMax(tgt_writer + c, i);   // numpy last-write-wins: max i
}

// ---------------------------------------------------------------------------
// K5: winning writers update rows: out[c] = relu(0.5*(Z[i] + Z[c]))
// ---------------------------------------------------------------------------
__global__ void k5_update(const int* __restrict__ chosen_arr,
                          const int* __restrict__ tgt_writer,
                          const float* __restrict__ Z,
                          float* __restrict__ out) {
    int i = blockIdx.x;
    int c = chosen_arr[i];
    if (c < 0 || tgt_writer[c] != i) return;
    int n = threadIdx.x;
    float z = 0.5f * (Z[(size_t)i * E_DIM + n] + Z[(size_t)c * E_DIM + n]);
    out[(size_t)c * E_DIM + n] = fmaxf(z, 0.f);
}

// ---------------------------------------------------------------------------
extern "C" void kernel_launch(void* const* d_in, const int* in_sizes, int n_in,
                              void* d_out, int out_size, void* d_ws,
                              size_t ws_size, hipStream_t stream) {
    const float* feat = (const float*)d_in[0];
    const float* We   = (const float*)d_in[1];
    const float* be   = (const float*)d_in[2];
    const float* W0   = (const float*)d_in[3];
    const float* b0   = (const float*)d_in[4];
    const float* W1   = (const float*)d_in[5];
    const float* b1   = (const float*)d_in[6];
    const float* Wlk  = (const float*)d_in[7];
    const float* blkp = (const float*)d_in[8];
    const float* Wa   = (const float*)d_in[9];
    const float* ba   = (const float*)d_in[10];
    const int* esrc   = (const int*)d_in[11];
    const int* edst   = (const int*)d_in[12];
    float* out = (float*)d_out;

    char* ws = (char*)d_ws;
    float* Z  = (float*)(ws);                               // 10,240,000
    float* P  = (float*)(ws + 10240000);                    // 20,480,000
    float* Qm = (float*)(ws + 30720000);                    // 20,480,000
    unsigned long long* keys  = (unsigned long long*)(ws + 51200000);  // 80,000
    unsigned long long* keys2 = (unsigned long long*)(ws + 51280000);  // 80,000
    float* logits = (float*)(ws + 51360000);                // 1,360,000
    float* lk_app = (float*)(ws + 52720000);                // 680,000
    int* list     = (int*)(ws + 53400000);                  // 680,000
    int* chosen_arr = (int*)(ws + 54080000);                // 40,000
    int* tgt_writer = (int*)(ws + 54120000);                // 40,000
    int* count      = (int*)(ws + 54160000);                // 128 (pad)
    f16* W1C        = (f16*)(ws + 54160128);                // 262,144

    hipMemsetAsync(keys, 0, 2 * N_NODES * sizeof(unsigned long long), stream);
    hipMemsetAsync(tgt_writer, 0xFF, N_NODES * sizeof(int), stream);
    hipMemsetAsync(count, 0, sizeof(int), stream);

    k1_emb<<<dim3((N_NODES + MT - 1) / MT), 256, 0, stream>>>(feat, We, be, Z, out);
    k2_pq<<<dim3((N_NODES + MT - 1) / MT, 4), 256, 0, stream>>>(out, W0, b0, P, Qm);
    k_prep<<<dim3(16), 256, 0, stream>>>(W1, W1C);
    k3_mfma<<<dim3((T_TOT + 63) / 64), 256, 0, stream>>>(
        P, Qm, W1C, b1, Wlk, blkp, esrc, edst, keys, lk_app);
    k_gather<<<dim3((T_TOT + 255) / 256), 256, 0, stream>>>(
        lk_app, keys, esrc, list, count);
    k_fixup<<<dim3(FIX_BLOCKS), 256, 0, stream>>>(
        P, Qm, W1, b1, Wlk, blkp, Wa, ba, esrc, edst, list, count, keys2, logits);
    k4_select<<<dim3((N_NODES + 255) / 256), 256, 0, stream>>>(
        keys2, edst, logits, chosen_arr, tgt_writer);
    k5_update<<<dim3(N_NODES), 256, 0, stream>>>(chosen_arr, tgt_writer, Z, out);
}

// Round 3
// 458.947 us; speedup vs baseline: 1.8198x; 1.0880x over previous
//
#include <hip/hip_runtime.h>
#include <stdint.h>

#define N_NODES 10000
#define F_IN    512
#define E_DIM   256
#define H0D     512
#define H1D     256
#define N_EDGES 160000
#define T_TOT   (N_EDGES + N_NODES)   // 170000

#define MT 64
#define KB 32
#define MARGIN2 5e-5f
#define LIST_CAP 20000
#define FIX_BLOCKS 64

typedef _Float16 f16;
typedef __attribute__((ext_vector_type(8))) _Float16 f16x8;
typedef __attribute__((ext_vector_type(4))) float f32x4;

// monotone map fp32 -> uint32 (order-preserving)
__device__ __forceinline__ unsigned int f2ord(float f) {
    unsigned int u = __float_as_uint(f);
    return (u & 0x80000000u) ? ~u : (u | 0x80000000u);
}
__device__ __forceinline__ float ord2f(unsigned int o) {
    unsigned int u = (o & 0x80000000u) ? (o & 0x7fffffffu) : ~o;
    return __uint_as_float(u);
}

// ---------------------------------------------------------------------------
// K_PREP_SPLIT: W fp32 [K x ld] slice -> chunked n-major split-f16 images.
//   Wh/Wl[c][n][kk] = split(W[rowoff + c*32 + kk][colbase + n])
// grid = nchunks, 256 threads.
// ---------------------------------------------------------------------------
__global__ void k_prep_split(const float* __restrict__ W, int ld, int rowoff,
                             int colbase, f16* __restrict__ Wh,
                             f16* __restrict__ Wl) {
    int c = blockIdx.x;
    int n = threadIdx.x;
    f16* dh = Wh + ((size_t)c * 256 + n) * 32;
    f16* dl = Wl + ((size_t)c * 256 + n) * 32;
    const float* src = W + (size_t)(rowoff + c * 32) * ld + colbase + n;
#pragma unroll
    for (int kk = 0; kk < 32; kk++) {
        float w = src[(size_t)kk * ld];
        f16 h = (f16)w;
        f16 l = (f16)(w - (float)h);
        dh[kk] = h;
        dl[kk] = l;
    }
}

// ===========================================================================
// Split-f16 GEMM tile: 64 rows x 256 cols, 256 threads (4 waves),
// wave tile 64x64 = 4x4 x mfma_f32_16x16x32_f16, 3 MFMA per fragment
// (ah*bh + ah*bl + al*bh) -> fp32-class accuracy (~2^-22 rel).
// C/D layout: col = lane&15, row = (lane>>4)*4 + reg.
// ===========================================================================

// ---------------------------------------------------------------------------
// K1: Z = feature @ We + be (pre-relu, cached);  out = relu(Z)  (= emb)
// ---------------------------------------------------------------------------
__global__ __launch_bounds__(256, 2) void k1_split(
        const float* __restrict__ feat, const f16* __restrict__ Bh_g,
        const f16* __restrict__ Bl_g, const float* __restrict__ be,
        float* __restrict__ Z, float* __restrict__ out) {
    __shared__ f16 Ah[64 * 32], Al_[64 * 32];
    __shared__ f16 Bh[256 * 32], Bl[256 * 32];
    const int tid = threadIdx.x;
    const int wave = tid >> 6, lane = tid & 63;
    const int quad = lane >> 4, l15 = lane & 15;
    const int mbase = blockIdx.x * 64;
    const int arow = tid >> 2, akp = tid & 3;
    const int gm_a = mbase + arow;
    const float* Arow = feat + (size_t)gm_a * F_IN + akp * 8;
    const bool rowok = (gm_a < N_NODES);

    f32x4 acc[4][4];
#pragma unroll
    for (int i = 0; i < 4; i++)
#pragma unroll
        for (int j = 0; j < 4; j++) acc[i][j] = (f32x4){0.f, 0.f, 0.f, 0.f};

    for (int k0 = 0; k0 < F_IN; k0 += 32) {
        float4 a0 = make_float4(0.f, 0.f, 0.f, 0.f), a1 = a0;
        if (rowok) {
            a0 = *(const float4*)(Arow + k0);
            a1 = *(const float4*)(Arow + k0 + 4);
        }
        f16x8 hv, lv;
        float av[8] = {a0.x, a0.y, a0.z, a0.w, a1.x, a1.y, a1.z, a1.w};
#pragma unroll
        for (int q = 0; q < 8; q++) {
            f16 h = (f16)av[q];
            hv[q] = h;
            lv[q] = (f16)(av[q] - (float)h);
        }
        const f16* bsh = Bh_g + (size_t)(k0 >> 5) * (256 * 32);
        const f16* bsl = Bl_g + (size_t)(k0 >> 5) * (256 * 32);
        f16x8 bvh[4], bvl[4];
#pragma unroll
        for (int r = 0; r < 4; r++) {
            bvh[r] = *(const f16x8*)(bsh + (size_t)(tid + 256 * r) * 8);
            bvl[r] = *(const f16x8*)(bsl + (size_t)(tid + 256 * r) * 8);
        }
        *(f16x8*)(Ah + arow * 32 + akp * 8) = hv;
        *(f16x8*)(Al_ + arow * 32 + akp * 8) = lv;
#pragma unroll
        for (int r = 0; r < 4; r++) {
            *(f16x8*)(Bh + (size_t)(tid + 256 * r) * 8) = bvh[r];
            *(f16x8*)(Bl + (size_t)(tid + 256 * r) * 8) = bvl[r];
        }
        __syncthreads();

        f16x8 afh[4], afl[4], bfh[4], bfl[4];
#pragma unroll
        for (int rt = 0; rt < 4; rt++) {
            afh[rt] = *(const f16x8*)(Ah + (rt * 16 + l15) * 32 + quad * 8);
            afl[rt] = *(const f16x8*)(Al_ + (rt * 16 + l15) * 32 + quad * 8);
        }
#pragma unroll
        for (int ct = 0; ct < 4; ct++) {
            bfh[ct] = *(const f16x8*)(Bh + (wave * 64 + ct * 16 + l15) * 32 + quad * 8);
            bfl[ct] = *(const f16x8*)(Bl + (wave * 64 + ct * 16 + l15) * 32 + quad * 8);
        }
#pragma unroll
        for (int rt = 0; rt < 4; rt++)
#pragma unroll
            for (int ct = 0; ct < 4; ct++) {
                acc[rt][ct] = __builtin_amdgcn_mfma_f32_16x16x32_f16(
                    afh[rt], bfh[ct], acc[rt][ct], 0, 0, 0);
                acc[rt][ct] = __builtin_amdgcn_mfma_f32_16x16x32_f16(
                    afl[rt], bfh[ct], acc[rt][ct], 0, 0, 0);
                acc[rt][ct] = __builtin_amdgcn_mfma_f32_16x16x32_f16(
                    afh[rt], bfl[ct], acc[rt][ct], 0, 0, 0);
            }
        __syncthreads();
    }

#pragma unroll
    for (int ct = 0; ct < 4; ct++) {
        int n = wave * 64 + ct * 16 + l15;
        float bb = be[n];
#pragma unroll
        for (int rt = 0; rt < 4; rt++)
#pragma unroll
            for (int reg = 0; reg < 4; reg++) {
                int gm = mbase + rt * 16 + quad * 4 + reg;
                if (gm < N_NODES) {
                    float z = acc[rt][ct][reg] + bb;
                    Z[(size_t)gm * E_DIM + n] = z;
                    out[(size_t)gm * E_DIM + n] = fmaxf(z, 0.f);
                }
            }
    }
}

// ---------------------------------------------------------------------------
// K2: P' = emb @ W0[0:256,:] + b0 ; Q = emb @ W0[256:512,:]
// blockIdx.y = group g: (P|Q) x (col 0-255 | 256-511). K=256 (8 chunks).
// ---------------------------------------------------------------------------
__global__ __launch_bounds__(256, 2) void k2_split(
        const float* __restrict__ emb, const f16* __restrict__ W0Ch,
        const f16* __restrict__ W0Cl, const float* __restrict__ b0,
        float* __restrict__ P, float* __restrict__ Qm) {
    __shared__ f16 Ah[64 * 32], Al_[64 * 32];
    __shared__ f16 Bh[256 * 32], Bl[256 * 32];
    const int tid = threadIdx.x;
    const int wave = tid >> 6, lane = tid & 63;
    const int quad = lane >> 4, l15 = lane & 15;
    const int mbase = blockIdx.x * 64;
    const int g = blockIdx.y;
    const int isQ = (g >= 2);
    const int colbase = (g & 1) * 256;
    const int arow = tid >> 2, akp = tid & 3;
    const int gm_a = mbase + arow;
    const float* Arow = emb + (size_t)gm_a * E_DIM + akp * 8;
    const bool rowok = (gm_a < N_NODES);
    const f16* Bh_g = W0Ch + (size_t)g * 8 * 256 * 32;
    const f16* Bl_g = W0Cl + (size_t)g * 8 * 256 * 32;

    f32x4 acc[4][4];
#pragma unroll
    for (int i = 0; i < 4; i++)
#pragma unroll
        for (int j = 0; j < 4; j++) acc[i][j] = (f32x4){0.f, 0.f, 0.f, 0.f};

    for (int k0 = 0; k0 < E_DIM; k0 += 32) {
        float4 a0 = make_float4(0.f, 0.f, 0.f, 0.f), a1 = a0;
        if (rowok) {
            a0 = *(const float4*)(Arow + k0);
            a1 = *(const float4*)(Arow + k0 + 4);
        }
        f16x8 hv, lv;
        float av[8] = {a0.x, a0.y, a0.z, a0.w, a1.x, a1.y, a1.z, a1.w};
#pragma unroll
        for (int q = 0; q < 8; q++) {
            f16 h = (f16)av[q];
            hv[q] = h;
            lv[q] = (f16)(av[q] - (float)h);
        }
        const f16* bsh = Bh_g + (size_t)(k0 >> 5) * (256 * 32);
        const f16* bsl = Bl_g + (size_t)(k0 >> 5) * (256 * 32);
        f16x8 bvh[4], bvl[4];
#pragma unroll
        for (int r = 0; r < 4; r++) {
            bvh[r] = *(const f16x8*)(bsh + (size_t)(tid + 256 * r) * 8);
            bvl[r] = *(const f16x8*)(bsl + (size_t)(tid + 256 * r) * 8);
        }
        *(f16x8*)(Ah + arow * 32 + akp * 8) = hv;
        *(f16x8*)(Al_ + arow * 32 + akp * 8) = lv;
#pragma unroll
        for (int r = 0; r < 4; r++) {
            *(f16x8*)(Bh + (size_t)(tid + 256 * r) * 8) = bvh[r];
            *(f16x8*)(Bl + (size_t)(tid + 256 * r) * 8) = bvl[r];
        }
        __syncthreads();

        f16x8 afh[4], afl[4], bfh[4], bfl[4];
#pragma unroll
        for (int rt = 0; rt < 4; rt++) {
            afh[rt] = *(const f16x8*)(Ah + (rt * 16 + l15) * 32 + quad * 8);
            afl[rt] = *(const f16x8*)(Al_ + (rt * 16 + l15) * 32 + quad * 8);
        }
#pragma unroll
        for (int ct = 0; ct < 4; ct++) {
            bfh[ct] = *(const f16x8*)(Bh + (wave * 64 + ct * 16 + l15) * 32 + quad * 8);
            bfl[ct] = *(const f16x8*)(Bl + (wave * 64 + ct * 16 + l15) * 32 + quad * 8);
        }
#pragma unroll
        for (int rt = 0; rt < 4; rt++)
#pragma unroll
            for (int ct = 0; ct < 4; ct++) {
                acc[rt][ct] = __builtin_amdgcn_mfma_f32_16x16x32_f16(
                    afh[rt], bfh[ct], acc[rt][ct], 0, 0, 0);
                acc[rt][ct] = __builtin_amdgcn_mfma_f32_16x16x32_f16(
                    afl[rt], bfh[ct], acc[rt][ct], 0, 0, 0);
                acc[rt][ct] = __builtin_amdgcn_mfma_f32_16x16x32_f16(
                    afh[rt], bfl[ct], acc[rt][ct], 0, 0, 0);
            }
        __syncthreads();
    }

    float* dst = isQ ? Qm : P;
#pragma unroll
    for (int ct = 0; ct < 4; ct++) {
        int n = wave * 64 + ct * 16 + l15;
        float bb = isQ ? 0.f : b0[colbase + n];
#pragma unroll
        for (int rt = 0; rt < 4; rt++)
#pragma unroll
            for (int reg = 0; reg < 4; reg++) {
                int gm = mbase + rt * 16 + quad * 4 + reg;
                if (gm < N_NODES)
                    dst[(size_t)gm * H0D + colbase + n] = acc[rt][ct][reg] + bb;
            }
    }
}

// ---------------------------------------------------------------------------
// K3: per entry t: h1 = relu(P[seg]+Q[dst]); h = relu(h1@W1+b1) via split-f16;
// epilogue: lk, logits (fp32-class accurate). atomicMax packed (lk,t) per seg.
// ---------------------------------------------------------------------------
__global__ __launch_bounds__(256, 2) void k3_split(
        const float* __restrict__ P, const float* __restrict__ Qm,
        const f16* __restrict__ W1Ch, const f16* __restrict__ W1Cl,
        const float* __restrict__ b1, const float* __restrict__ Wlk,
        const float* __restrict__ blkp, const float* __restrict__ Wa,
        const float* __restrict__ ba, const int* __restrict__ esrc,
        const int* __restrict__ edst, unsigned long long* __restrict__ keys,
        float* __restrict__ lk_app, float* __restrict__ logits) {
    __shared__ f16 Ah[64 * 32], Al_[64 * 32];
    __shared__ f16 Bh[256 * 32], Bl[256 * 32];
    __shared__ float redA[64][5], redB[64][5], redC[64][5];
    __shared__ int s_seg[64], s_dst[64];
    const int tid = threadIdx.x;
    const int wave = tid >> 6, lane = tid & 63;
    const int quad = lane >> 4, l15 = lane & 15;
    const int tbase = blockIdx.x * 64;

    if (tid < 64) {
        int t = tbase + tid;
        int s = 0, d = -1;
        if (t < N_EDGES) { s = esrc[t]; d = edst[t]; }
        else if (t < T_TOT) { s = t - N_EDGES; }
        s_seg[tid] = s;
        s_dst[tid] = d;
    }
    __syncthreads();

    const int arow = tid >> 2, akp = tid & 3;
    const int sA = s_seg[arow], dA = s_dst[arow];
    const float* Prow = P + (size_t)sA * H0D + akp * 8;
    const float* Qrow = Qm + (size_t)(dA >= 0 ? dA : 0) * H0D + akp * 8;
    const bool hasQ = (dA >= 0);

    f32x4 acc[4][4];
#pragma unroll
    for (int i = 0; i < 4; i++)
#pragma unroll
        for (int j = 0; j < 4; j++) acc[i][j] = (f32x4){0.f, 0.f, 0.f, 0.f};

    for (int k0 = 0; k0 < H0D; k0 += 32) {
        float4 a0 = *(const float4*)(Prow + k0);
        float4 a1 = *(const float4*)(Prow + k0 + 4);
        if (hasQ) {
            float4 q0 = *(const float4*)(Qrow + k0);
            float4 q1 = *(const float4*)(Qrow + k0 + 4);
            a0.x += q0.x; a0.y += q0.y; a0.z += q0.z; a0.w += q0.w;
            a1.x += q1.x; a1.y += q1.y; a1.z += q1.z; a1.w += q1.w;
        }
        float av[8] = {fmaxf(a0.x, 0.f), fmaxf(a0.y, 0.f), fmaxf(a0.z, 0.f),
                       fmaxf(a0.w, 0.f), fmaxf(a1.x, 0.f), fmaxf(a1.y, 0.f),
                       fmaxf(a1.z, 0.f), fmaxf(a1.w, 0.f)};
        f16x8 hv, lv;
#pragma unroll
        for (int q = 0; q < 8; q++) {
            f16 h = (f16)av[q];
            hv[q] = h;
            lv[q] = (f16)(av[q] - (float)h);
        }
        const f16* bsh = W1Ch + (size_t)(k0 >> 5) * (256 * 32);
        const f16* bsl = W1Cl + (size_t)(k0 >> 5) * (256 * 32);
        f16x8 bvh[4], bvl[4];
#pragma unroll
        for (int r = 0; r < 4; r++) {
            bvh[r] = *(const f16x8*)(bsh + (size_t)(tid + 256 * r) * 8);
            bvl[r] = *(const f16x8*)(bsl + (size_t)(tid + 256 * r) * 8);
        }
        *(f16x8*)(Ah + arow * 32 + akp * 8) = hv;
        *(f16x8*)(Al_ + arow * 32 + akp * 8) = lv;
#pragma unroll
        for (int r = 0; r < 4; r++) {
            *(f16x8*)(Bh + (size_t)(tid + 256 * r) * 8) = bvh[r];
            *(f16x8*)(Bl + (size_t)(tid + 256 * r) * 8) = bvl[r];
        }
        __syncthreads();

        f16x8 afh[4], afl[4], bfh[4], bfl[4];
#pragma unroll
        for (int rt = 0; rt < 4; rt++) {
            afh[rt] = *(const f16x8*)(Ah + (rt * 16 + l15) * 32 + quad * 8);
            afl[rt] = *(const f16x8*)(Al_ + (rt * 16 + l15) * 32 + quad * 8);
        }
#pragma unroll
        for (int ct = 0; ct < 4; ct++) {
            bfh[ct] = *(const f16x8*)(Bh + (wave * 64 + ct * 16 + l15) * 32 + quad * 8);
            bfl[ct] = *(const f16x8*)(Bl + (wave * 64 + ct * 16 + l15) * 32 + quad * 8);
        }
#pragma unroll
        for (int rt = 0; rt < 4; rt++)
#pragma unroll
            for (int ct = 0; ct < 4; ct++) {
                acc[rt][ct] = __builtin_amdgcn_mfma_f32_16x16x32_f16(
                    afh[rt], bfh[ct], acc[rt][ct], 0, 0, 0);
                acc[rt][ct] = __builtin_amdgcn_mfma_f32_16x16x32_f16(
                    afl[rt], bfh[ct], acc[rt][ct], 0, 0, 0);
                acc[rt][ct] = __builtin_amdgcn_mfma_f32_16x16x32_f16(
                    afh[rt], bfl[ct], acc[rt][ct], 0, 0, 0);
            }
        __syncthreads();
    }

    // epilogue: h = relu(acc + b1); three 256-dots (lk, logit0, logit1)
    float wl[4], wa0[4], wa1[4], bb[4];
#pragma unroll
    for (int ct = 0; ct < 4; ct++) {
        int n = wave * 64 + ct * 16 + l15;
        wl[ct] = Wlk[n];
        wa0[ct] = Wa[2 * n];
        wa1[ct] = Wa[2 * n + 1];
        bb[ct] = b1[n];
    }
#pragma unroll
    for (int rt = 0; rt < 4; rt++) {
#pragma unroll
        for (int reg = 0; reg < 4; reg++) {
            float plk = 0.f, p0 = 0.f, p1 = 0.f;
#pragma unroll
            for (int ct = 0; ct < 4; ct++) {
                float h = fmaxf(acc[rt][ct][reg] + bb[ct], 0.f);
                plk = fmaf(h, wl[ct], plk);
                p0 = fmaf(h, wa0[ct], p0);
                p1 = fmaf(h, wa1[ct], p1);
            }
#pragma unroll
            for (int off = 8; off >= 1; off >>= 1) {
                plk += __shfl_xor(plk, off);
                p0 += __shfl_xor(p0, off);
                p1 += __shfl_xor(p1, off);
            }
            if (l15 == 0) {
                int row = rt * 16 + quad * 4 + reg;
                redA[row][wave] = plk;
                redB[row][wave] = p0;
                redC[row][wave] = p1;
            }
        }
    }
    __syncthreads();
    if (tid < 64) {
        int t = tbase + tid;
        if (t < T_TOT) {
            float lk = redA[tid][0] + redA[tid][1] + redA[tid][2] + redA[tid][3] + blkp[0];
            float l0 = redB[tid][0] + redB[tid][1] + redB[tid][2] + redB[tid][3] + ba[0];
            float l1 = redC[tid][0] + redC[tid][1] + redC[tid][2] + redC[tid][3] + ba[1];
            lk_app[t] = lk;
            logits[2 * t] = l0;
            logits[2 * t + 1] = l1;
            unsigned long long key =
                ((unsigned long long)f2ord(lk) << 32) | (unsigned int)t;
            atomicMax(keys + s_seg[tid], key);
        }
    }
}

// ---------------------------------------------------------------------------
// K_GA: count candidates within MARGIN2 of seg best (approx).
// ---------------------------------------------------------------------------
__global__ void k_ga(const float* __restrict__ lk_app,
                     const unsigned long long* __restrict__ keys,
                     const int* __restrict__ esrc, int* __restrict__ seg_cnt) {
    int t = blockIdx.x * 256 + threadIdx.x;
    if (t >= T_TOT) return;
    int seg = (t < N_EDGES) ? esrc[t] : t - N_EDGES;
    float best = ord2f((unsigned int)(keys[seg] >> 32));
    if (lk_app[t] >= best - MARGIN2) atomicAdd(seg_cnt + seg, 1);
}

// ---------------------------------------------------------------------------
// K_GB: gather candidates belonging to TIED segments only (cnt >= 2).
// ---------------------------------------------------------------------------
__global__ void k_gb(const float* __restrict__ lk_app,
                     const unsigned long long* __restrict__ keys,
                     const int* __restrict__ esrc,
                     const int* __restrict__ seg_cnt,
                     int* __restrict__ list, int* __restrict__ count) {
    int t = blockIdx.x * 256 + threadIdx.x;
    if (t >= T_TOT) return;
    int seg = (t < N_EDGES) ? esrc[t] : t - N_EDGES;
    if (seg_cnt[seg] < 2) return;
    float best = ord2f((unsigned int)(keys[seg] >> 32));
    if (lk_app[t] >= best - MARGIN2) {
        int idx = atomicAdd(count, 1);
        if (idx < LIST_CAP) list[idx] = t;
    }
}

// ---------------------------------------------------------------------------
// K_FIXUP: exact fp32 recompute of lk + logits for tied-segment candidates.
// ---------------------------------------------------------------------------
__global__ __launch_bounds__(256, 2) void k_fixup(
        const float* __restrict__ P, const float* __restrict__ Qm,
        const float* __restrict__ W1, const float* __restrict__ b1,
        const float* __restrict__ Wlk, const float* __restrict__ blkp,
        const float* __restrict__ Wa, const float* __restrict__ ba,
        const int* __restrict__ esrc, const int* __restrict__ edst,
        const int* __restrict__ list, const int* __restrict__ count,
        unsigned long long* __restrict__ keys2, float* __restrict__ logits) {
    __shared__ float Al[MT][KB + 4];
    __shared__ float Bl[KB][256];
    __shared__ int s_seg[MT];
    __shared__ int s_dst[MT];
    __shared__ int s_t[MT];
    const int tid = threadIdx.x;
    const int rg = tid >> 5, cg = tid & 31;
    int cnt = *count;
    if (cnt > LIST_CAP) cnt = LIST_CAP;
    const int nch = (cnt + MT - 1) / MT;

    for (int ch = blockIdx.x; ch < nch; ch += gridDim.x) {
        if (tid < MT) {
            int li = ch * MT + tid;
            int t = (li < cnt) ? list[li] : -1;
            int s = 0, d = -1;
            if (t >= 0) {
                if (t < N_EDGES) { s = esrc[t]; d = edst[t]; }
                else { s = t - N_EDGES; }
            }
            s_t[tid] = t;
            s_seg[tid] = s;
            s_dst[tid] = d;
        }
        __syncthreads();

        float acc[8][8];
#pragma unroll
        for (int i = 0; i < 8; i++)
#pragma unroll
            for (int j = 0; j < 8; j++) acc[i][j] = 0.f;

        for (int k0 = 0; k0 < H0D; k0 += KB) {
#pragma unroll
            for (int r = 0; r < 2; r++) {
                int f = tid + 256 * r;
                int m = f >> 3, q = f & 7;
                int s = s_seg[m], d = s_dst[m];
                float4 v = *(const float4*)(P + (size_t)s * H0D + k0 + q * 4);
                if (d >= 0) {
                    float4 w = *(const float4*)(Qm + (size_t)d * H0D + k0 + q * 4);
                    v.x += w.x; v.y += w.y; v.z += w.z; v.w += w.w;
                }
                v.x = fmaxf(v.x, 0.f); v.y = fmaxf(v.y, 0.f);
                v.z = fmaxf(v.z, 0.f); v.w = fmaxf(v.w, 0.f);
                *(float4*)(&Al[m][q * 4]) = v;
            }
#pragma unroll
            for (int r = 0; r < 8; r++) {
                int f = tid + 256 * r;
                int kk = f >> 6, q = f & 63;
                *(float4*)(&Bl[kk][q * 4]) =
                    *(const float4*)(W1 + (size_t)(k0 + kk) * H1D + q * 4);
            }
            __syncthreads();
            for (int kk = 0; kk < KB; kk++) {
                float a[8], b[8];
#pragma unroll
                for (int i = 0; i < 8; i++) a[i] = Al[rg * 8 + i][kk];
#pragma unroll
                for (int j = 0; j < 8; j++) b[j] = Bl[kk][cg + 32 * j];
#pragma unroll
                for (int i = 0; i < 8; i++)
#pragma unroll
                    for (int j = 0; j < 8; j++)
                        acc[i][j] = fmaf(a[i], b[j], acc[i][j]);
            }
            __syncthreads();
        }

        float wl[8], wa0[8], wa1[8], bb1[8];
#pragma unroll
        for (int j = 0; j < 8; j++) {
            int n = cg + 32 * j;
            wl[j] = Wlk[n];
            wa0[j] = Wa[2 * n];
            wa1[j] = Wa[2 * n + 1];
            bb1[j] = b1[n];
        }
#pragma unroll
        for (int i = 0; i < 8; i++) {
            float plk = 0.f, p0 = 0.f, p1 = 0.f;
#pragma unroll
            for (int j = 0; j < 8; j++) {
                float h = fmaxf(acc[i][j] + bb1[j], 0.f);
                plk = fmaf(h, wl[j], plk);
                p0 = fmaf(h, wa0[j], p0);
                p1 = fmaf(h, wa1[j], p1);
            }
#pragma unroll
            for (int off = 16; off >= 1; off >>= 1) {
                plk += __shfl_xor(plk, off);
                p0 += __shfl_xor(p0, off);
                p1 += __shfl_xor(p1, off);
            }
            if (cg == 0) {
                int m = rg * 8 + i;
                int t = s_t[m];
                if (t >= 0) {
                    float lk = plk + blkp[0];
                    logits[2 * t] = p0 + ba[0];
                    logits[2 * t + 1] = p1 + ba[1];
                    unsigned long long key =
                        ((unsigned long long)f2ord(lk) << 32) | (unsigned int)t;
                    atomicMax(keys2 + s_seg[m], key);
                }
            }
        }
        __syncthreads();
    }
}

// ---------------------------------------------------------------------------
// K4: winner per node (exact keys2 for tied segments, else approx keys);
// at-bit from logits; last-writer claim on target.
// ---------------------------------------------------------------------------
__global__ void k4_select(const unsigned long long* __restrict__ keys,
                          const unsigned long long* __restrict__ keys2,
                          const int* __restrict__ seg_cnt,
                          const int* __restrict__ edst,
                          const float* __restrict__ logits,
                          int* __restrict__ chosen_arr,
                          int* __restrict__ tgt_writer) {
    int i = blockIdx.x * 256 + threadIdx.x;
    if (i >= N_NODES) return;
    unsigned long long key = keys[i];
    if (seg_cnt[i] >= 2) {
        unsigned long long k2v = keys2[i];
        if (k2v != 0ull) key = k2v;
    }
    int t = (int)(key & 0xFFFFFFFFull);
    int chosen = (t < N_EDGES) ? edst[t] : -1;
    float lg0 = logits[2 * t], lg1 = logits[2 * t + 1];
    int at1 = (lg1 > lg0) ? 1 : 0;   // argmax: tie -> index 0
    int c = (chosen >= 0 && at1) ? chosen : -1;
    chosen_arr[i] = c;
    if (c >= 0) atomicMax(tgt_writer + c, i);   // numpy last-write-wins: max i
}

// ---------------------------------------------------------------------------
// K5: winning writers update rows: out[c] = relu(0.5*(Z[i] + Z[c]))
// ---------------------------------------------------------------------------
__global__ void k5_update(const int* __restrict__ chosen_arr,
                          const int* __restrict__ tgt_writer,
                          const float* __restrict__ Z,
                          float* __restrict__ out) {
    int i = blockIdx.x;
    int c = chosen_arr[i];
    if (c < 0 || tgt_writer[c] != i) return;
    int n = threadIdx.x;
    float z = 0.5f * (Z[(size_t)i * E_DIM + n] + Z[(size_t)c * E_DIM + n]);
    out[(size_t)c * E_DIM + n] = fmaxf(z, 0.f);
}

// ---------------------------------------------------------------------------
extern "C" void kernel_launch(void* const* d_in, const int* in_sizes, int n_in,
                              void* d_out, int out_size, void* d_ws,
                              size_t ws_size, hipStream_t stream) {
    const float* feat = (const float*)d_in[0];
    const float* We   = (const float*)d_in[1];
    const float* be   = (const float*)d_in[2];
    const float* W0   = (const float*)d_in[3];
    const float* b0   = (const float*)d_in[4];
    const float* W1   = (const float*)d_in[5];
    const float* b1   = (const float*)d_in[6];
    const float* Wlk  = (const float*)d_in[7];
    const float* blkp = (const float*)d_in[8];
    const float* Wa   = (const float*)d_in[9];
    const float* ba   = (const float*)d_in[10];
    const int* esrc   = (const int*)d_in[11];
    const int* edst   = (const int*)d_in[12];
    float* out = (float*)d_out;

    char* ws = (char*)d_ws;
    size_t off = 0;
    float* Z  = (float*)(ws + off); off += (size_t)N_NODES * E_DIM * 4;     // 10.24MB
    float* P  = (float*)(ws + off); off += (size_t)N_NODES * H0D * 4;       // 20.48MB
    float* Qm = (float*)(ws + off); off += (size_t)N_NODES * H0D * 4;       // 20.48MB
    unsigned long long* keys  = (unsigned long long*)(ws + off); off += N_NODES * 8;
    unsigned long long* keys2 = (unsigned long long*)(ws + off); off += N_NODES * 8;
    float* logits = (float*)(ws + off); off += (size_t)T_TOT * 2 * 4;       // 1.36MB
    float* lk_app = (float*)(ws + off); off += (size_t)T_TOT * 4;           // 0.68MB
    int* list     = (int*)(ws + off); off += (size_t)LIST_CAP * 4;
    int* seg_cnt  = (int*)(ws + off); off += N_NODES * 4;
    int* chosen_arr = (int*)(ws + off); off += N_NODES * 4;
    int* tgt_writer = (int*)(ws + off); off += N_NODES * 4;
    int* count      = (int*)(ws + off); off += 128;
    f16* WeC_h = (f16*)(ws + off); off += (size_t)16 * 256 * 32 * 2;
    f16* WeC_l = (f16*)(ws + off); off += (size_t)16 * 256 * 32 * 2;
    f16* W1C_h = (f16*)(ws + off); off += (size_t)16 * 256 * 32 * 2;
    f16* W1C_l = (f16*)(ws + off); off += (size_t)16 * 256 * 32 * 2;
    f16* W0C_h = (f16*)(ws + off); off += (size_t)32 * 256 * 32 * 2;
    f16* W0C_l = (f16*)(ws + off); off += (size_t)32 * 256 * 32 * 2;

    hipMemsetAsync(keys, 0, N_NODES * 8, stream);
    hipMemsetAsync(keys2, 0, N_NODES * 8, stream);
    hipMemsetAsync(seg_cnt, 0, N_NODES * 4, stream);
    hipMemsetAsync(tgt_writer, 0xFF, N_NODES * 4, stream);
    hipMemsetAsync(count, 0, sizeof(int), stream);

    // weight prep: split-f16 chunked images
    k_prep_split<<<dim3(16), 256, 0, stream>>>(We, E_DIM, 0, 0, WeC_h, WeC_l);
    k_prep_split<<<dim3(16), 256, 0, stream>>>(W1, H1D, 0, 0, W1C_h, W1C_l);
    for (int g = 0; g < 4; g++) {
        int rowoff = (g >= 2) ? 256 : 0;
        int colbase = (g & 1) * 256;
        k_prep_split<<<dim3(8), 256, 0, stream>>>(
            W0, H0D, rowoff, colbase,
            W0C_h + (size_t)g * 8 * 256 * 32, W0C_l + (size_t)g * 8 * 256 * 32);
    }

    k1_split<<<dim3((N_NODES + 63) / 64), 256, 0, stream>>>(
        feat, WeC_h, WeC_l, be, Z, out);
    k2_split<<<dim3((N_NODES + 63) / 64, 4), 256, 0, stream>>>(
        out, W0C_h, W0C_l, b0, P, Qm);
    k3_split<<<dim3((T_TOT + 63) / 64), 256, 0, stream>>>(
        P, Qm, W1C_h, W1C_l, b1, Wlk, blkp, Wa, ba, esrc, edst,
        keys, lk_app, logits);
    k_ga<<<dim3((T_TOT + 255) / 256), 256, 0, stream>>>(lk_app, keys, esrc, seg_cnt);
    k_gb<<<dim3((T_TOT + 255) / 256), 256, 0, stream>>>(
        lk_app, keys, esrc, seg_cnt, list, count);
    k_fixup<<<dim3(FIX_BLOCKS), 256, 0, stream>>>(
        P, Qm, W1, b1, Wlk, blkp, Wa, ba, esrc, edst, list, count, keys2, logits);
    k4_select<<<dim3((N_NODES + 255) / 256), 256, 0, stream>>>(
        keys, keys2, seg_cnt, edst, logits, chosen_arr, tgt_writer);
    k5_update<<<dim3(N_NODES), 256, 0, stream>>>(chosen_arr, tgt_writer, Z, out);
}

// Round 4
// 431.740 us; speedup vs baseline: 1.9345x; 1.0630x over previous
//
#include <hip/hip_runtime.h>
#include <stdint.h>

#define N_NODES 10000
#define F_IN    512
#define E_DIM   256
#define H0D     512
#define H1D     256
#define N_EDGES 160000
#define T_TOT   (N_EDGES + N_NODES)   // 170000

#define MT 64
#define KB 32
#define MARGIN_LK 4e-3f
#define MARGIN_L  4e-3f
#define LIST_CAP 20000
#define FIX_BLOCKS 64
#define LP 36                       // padded LDS row stride in f16 (72B)

typedef _Float16 f16;
typedef __attribute__((ext_vector_type(8))) _Float16 f16x8;
typedef __attribute__((ext_vector_type(4))) float f32x4;

// monotone map fp32 -> uint32 (order-preserving)
__device__ __forceinline__ unsigned int f2ord(float f) {
    unsigned int u = __float_as_uint(f);
    return (u & 0x80000000u) ? ~u : (u | 0x80000000u);
}
__device__ __forceinline__ float ord2f(unsigned int o) {
    unsigned int u = (o & 0x80000000u) ? (o & 0x7fffffffu) : ~o;
    return __uint_as_float(u);
}

// ---------------------------------------------------------------------------
// K_PREP_ALL: all three weight matrices -> chunked n-major split-f16 images.
// blocks 0-15: We (16 chunks); 16-31: W1; 32-63: W0 (4 groups x 8 chunks).
//   img[c][n][kk] = split(W[rowoff + c*32 + kk][colbase + n])
// ---------------------------------------------------------------------------
__global__ void k_prep_all(const float* __restrict__ We,
                           const float* __restrict__ W1,
                           const float* __restrict__ W0,
                           f16* __restrict__ WeC_h, f16* __restrict__ WeC_l,
                           f16* __restrict__ W1C_h, f16* __restrict__ W1C_l,
                           f16* __restrict__ W0C_h, f16* __restrict__ W0C_l) {
    int b = blockIdx.x;
    int n = threadIdx.x;
    const float* W;
    int ld, rowoff, colbase, c;
    f16 *dh_base, *dl_base;
    if (b < 16) {
        W = We; ld = E_DIM; rowoff = 0; colbase = 0; c = b;
        dh_base = WeC_h; dl_base = WeC_l;
    } else if (b < 32) {
        W = W1; ld = H1D; rowoff = 0; colbase = 0; c = b - 16;
        dh_base = W1C_h; dl_base = W1C_l;
    } else {
        int g = (b - 32) >> 3; c = (b - 32) & 7;
        rowoff = (g >= 2) ? 256 : 0; colbase = (g & 1) * 256;
        W = W0; ld = H0D;
        dh_base = W0C_h + (size_t)g * 8 * 256 * 32;
        dl_base = W0C_l + (size_t)g * 8 * 256 * 32;
    }
    f16* dh = dh_base + ((size_t)c * 256 + n) * 32;
    f16* dl = dl_base + ((size_t)c * 256 + n) * 32;
    const float* src = W + (size_t)(rowoff + c * 32) * ld + colbase + n;
#pragma unroll
    for (int kk = 0; kk < 32; kk++) {
        float w = src[(size_t)kk * ld];
        f16 h = (f16)w;
        f16 l = (f16)(w - (float)h);
        dh[kk] = h;
        dl[kk] = l;
    }
}

// ===========================================================================
// Split-f16 GEMM tile: 64 rows x 256 cols, 256 threads (4 waves),
// wave tile 64x64 = 4x4 x mfma_f32_16x16x32_f16.
// k1/k2: 3 MFMA/frag (ah*bh + al*bh + ah*bl) -> ~2^-22 rel (fp32-class).
// k3:    2 MFMA/frag (ah*bh + ah*bl)         -> ~2^-11-on-A noise, margin-
//        protected discrete decisions + exact fixup.
// C/D layout: col = lane&15, row = (lane>>4)*4 + reg.
// LDS rows padded to LP=36 f16 (72B) -> 2-way max bank alias (free).
// ===========================================================================

// ---------------------------------------------------------------------------
// K1: Z = feature @ We + be (pre-relu, cached);  out = relu(Z)  (= emb)
// ---------------------------------------------------------------------------
__global__ __launch_bounds__(256, 3) void k1_split(
        const float* __restrict__ feat, const f16* __restrict__ Bh_g,
        const f16* __restrict__ Bl_g, const float* __restrict__ be,
        float* __restrict__ Z, float* __restrict__ out) {
    __shared__ f16 Ah[64 * LP], Al_[64 * LP];
    __shared__ f16 Bh[256 * LP], Bl[256 * LP];
    const int tid = threadIdx.x;
    const int wave = tid >> 6, lane = tid & 63;
    const int quad = lane >> 4, l15 = lane & 15;
    const int mbase = blockIdx.x * 64;
    const int arow = tid >> 2, akp = tid & 3;
    const int gm_a = mbase + arow;
    const float* Arow = feat + (size_t)gm_a * F_IN + akp * 8;
    const bool rowok = (gm_a < N_NODES);

    f32x4 acc[4][4];
#pragma unroll
    for (int i = 0; i < 4; i++)
#pragma unroll
        for (int j = 0; j < 4; j++) acc[i][j] = (f32x4){0.f, 0.f, 0.f, 0.f};

    for (int k0 = 0; k0 < F_IN; k0 += 32) {
        float4 a0 = make_float4(0.f, 0.f, 0.f, 0.f), a1 = a0;
        if (rowok) {
            a0 = *(const float4*)(Arow + k0);
            a1 = *(const float4*)(Arow + k0 + 4);
        }
        f16x8 hv, lv;
        float av[8] = {a0.x, a0.y, a0.z, a0.w, a1.x, a1.y, a1.z, a1.w};
#pragma unroll
        for (int q = 0; q < 8; q++) {
            f16 h = (f16)av[q];
            hv[q] = h;
            lv[q] = (f16)(av[q] - (float)h);
        }
        const f16* bsh = Bh_g + (size_t)(k0 >> 5) * (256 * 32);
        const f16* bsl = Bl_g + (size_t)(k0 >> 5) * (256 * 32);
        f16x8 bvh[4], bvl[4];
#pragma unroll
        for (int r = 0; r < 4; r++) {
            bvh[r] = *(const f16x8*)(bsh + (size_t)(tid + 256 * r) * 8);
            bvl[r] = *(const f16x8*)(bsl + (size_t)(tid + 256 * r) * 8);
        }
        *(f16x8*)(Ah + arow * LP + akp * 8) = hv;
        *(f16x8*)(Al_ + arow * LP + akp * 8) = lv;
#pragma unroll
        for (int r = 0; r < 4; r++) {
            int f = tid + 256 * r;
            int n = f >> 2, kb = (f & 3) * 8;
            *(f16x8*)(Bh + n * LP + kb) = bvh[r];
            *(f16x8*)(Bl + n * LP + kb) = bvl[r];
        }
        __syncthreads();

        f16x8 afh[4], afl[4], bfh[4], bfl[4];
#pragma unroll
        for (int rt = 0; rt < 4; rt++) {
            afh[rt] = *(const f16x8*)(Ah + (rt * 16 + l15) * LP + quad * 8);
            afl[rt] = *(const f16x8*)(Al_ + (rt * 16 + l15) * LP + quad * 8);
        }
#pragma unroll
        for (int ct = 0; ct < 4; ct++) {
            bfh[ct] = *(const f16x8*)(Bh + (wave * 64 + ct * 16 + l15) * LP + quad * 8);
            bfl[ct] = *(const f16x8*)(Bl + (wave * 64 + ct * 16 + l15) * LP + quad * 8);
        }
#pragma unroll
        for (int rt = 0; rt < 4; rt++)
#pragma unroll
            for (int ct = 0; ct < 4; ct++) {
                acc[rt][ct] = __builtin_amdgcn_mfma_f32_16x16x32_f16(
                    afh[rt], bfh[ct], acc[rt][ct], 0, 0, 0);
                acc[rt][ct] = __builtin_amdgcn_mfma_f32_16x16x32_f16(
                    afl[rt], bfh[ct], acc[rt][ct], 0, 0, 0);
                acc[rt][ct] = __builtin_amdgcn_mfma_f32_16x16x32_f16(
                    afh[rt], bfl[ct], acc[rt][ct], 0, 0, 0);
            }
        __syncthreads();
    }

#pragma unroll
    for (int ct = 0; ct < 4; ct++) {
        int n = wave * 64 + ct * 16 + l15;
        float bb = be[n];
#pragma unroll
        for (int rt = 0; rt < 4; rt++)
#pragma unroll
            for (int reg = 0; reg < 4; reg++) {
                int gm = mbase + rt * 16 + quad * 4 + reg;
                if (gm < N_NODES) {
                    float z = acc[rt][ct][reg] + bb;
                    Z[(size_t)gm * E_DIM + n] = z;
                    out[(size_t)gm * E_DIM + n] = fmaxf(z, 0.f);
                }
            }
    }
}

// ---------------------------------------------------------------------------
// K2: P' = emb @ W0[0:256,:] + b0 ; Q = emb @ W0[256:512,:]
// blockIdx.y = group g: (P|Q) x (col 0-255 | 256-511). K=256 (8 chunks).
// ---------------------------------------------------------------------------
__global__ __launch_bounds__(256, 3) void k2_split(
        const float* __restrict__ emb, const f16* __restrict__ W0Ch,
        const f16* __restrict__ W0Cl, const float* __restrict__ b0,
        float* __restrict__ P, float* __restrict__ Qm) {
    __shared__ f16 Ah[64 * LP], Al_[64 * LP];
    __shared__ f16 Bh[256 * LP], Bl[256 * LP];
    const int tid = threadIdx.x;
    const int wave = tid >> 6, lane = tid & 63;
    const int quad = lane >> 4, l15 = lane & 15;
    const int mbase = blockIdx.x * 64;
    const int g = blockIdx.y;
    const int isQ = (g >= 2);
    const int colbase = (g & 1) * 256;
    const int arow = tid >> 2, akp = tid & 3;
    const int gm_a = mbase + arow;
    const float* Arow = emb + (size_t)gm_a * E_DIM + akp * 8;
    const bool rowok = (gm_a < N_NODES);
    const f16* Bh_g = W0Ch + (size_t)g * 8 * 256 * 32;
    const f16* Bl_g = W0Cl + (size_t)g * 8 * 256 * 32;

    f32x4 acc[4][4];
#pragma unroll
    for (int i = 0; i < 4; i++)
#pragma unroll
        for (int j = 0; j < 4; j++) acc[i][j] = (f32x4){0.f, 0.f, 0.f, 0.f};

    for (int k0 = 0; k0 < E_DIM; k0 += 32) {
        float4 a0 = make_float4(0.f, 0.f, 0.f, 0.f), a1 = a0;
        if (rowok) {
            a0 = *(const float4*)(Arow + k0);
            a1 = *(const float4*)(Arow + k0 + 4);
        }
        f16x8 hv, lv;
        float av[8] = {a0.x, a0.y, a0.z, a0.w, a1.x, a1.y, a1.z, a1.w};
#pragma unroll
        for (int q = 0; q < 8; q++) {
            f16 h = (f16)av[q];
            hv[q] = h;
            lv[q] = (f16)(av[q] - (float)h);
        }
        const f16* bsh = Bh_g + (size_t)(k0 >> 5) * (256 * 32);
        const f16* bsl = Bl_g + (size_t)(k0 >> 5) * (256 * 32);
        f16x8 bvh[4], bvl[4];
#pragma unroll
        for (int r = 0; r < 4; r++) {
            bvh[r] = *(const f16x8*)(bsh + (size_t)(tid + 256 * r) * 8);
            bvl[r] = *(const f16x8*)(bsl + (size_t)(tid + 256 * r) * 8);
        }
        *(f16x8*)(Ah + arow * LP + akp * 8) = hv;
        *(f16x8*)(Al_ + arow * LP + akp * 8) = lv;
#pragma unroll
        for (int r = 0; r < 4; r++) {
            int f = tid + 256 * r;
            int n = f >> 2, kb = (f & 3) * 8;
            *(f16x8*)(Bh + n * LP + kb) = bvh[r];
            *(f16x8*)(Bl + n * LP + kb) = bvl[r];
        }
        __syncthreads();

        f16x8 afh[4], afl[4], bfh[4], bfl[4];
#pragma unroll
        for (int rt = 0; rt < 4; rt++) {
            afh[rt] = *(const f16x8*)(Ah + (rt * 16 + l15) * LP + quad * 8);
            afl[rt] = *(const f16x8*)(Al_ + (rt * 16 + l15) * LP + quad * 8);
        }
#pragma unroll
        for (int ct = 0; ct < 4; ct++) {
            bfh[ct] = *(const f16x8*)(Bh + (wave * 64 + ct * 16 + l15) * LP + quad * 8);
            bfl[ct] = *(const f16x8*)(Bl + (wave * 64 + ct * 16 + l15) * LP + quad * 8);
        }
#pragma unroll
        for (int rt = 0; rt < 4; rt++)
#pragma unroll
            for (int ct = 0; ct < 4; ct++) {
                acc[rt][ct] = __builtin_amdgcn_mfma_f32_16x16x32_f16(
                    afh[rt], bfh[ct], acc[rt][ct], 0, 0, 0);
                acc[rt][ct] = __builtin_amdgcn_mfma_f32_16x16x32_f16(
                    afl[rt], bfh[ct], acc[rt][ct], 0, 0, 0);
                acc[rt][ct] = __builtin_amdgcn_mfma_f32_16x16x32_f16(
                    afh[rt], bfl[ct], acc[rt][ct], 0, 0, 0);
            }
        __syncthreads();
    }

    float* dst = isQ ? Qm : P;
#pragma unroll
    for (int ct = 0; ct < 4; ct++) {
        int n = wave * 64 + ct * 16 + l15;
        float bb = isQ ? 0.f : b0[colbase + n];
#pragma unroll
        for (int rt = 0; rt < 4; rt++)
#pragma unroll
            for (int reg = 0; reg < 4; reg++) {
                int gm = mbase + rt * 16 + quad * 4 + reg;
                if (gm < N_NODES)
                    dst[(size_t)gm * H0D + colbase + n] = acc[rt][ct][reg] + bb;
            }
    }
}

// ---------------------------------------------------------------------------
// K3 (2-term): per entry t: h1 = relu(P[seg]+Q[dst]); h=relu(h1@W1+b1);
// lk + logits (~1e-3-class accurate). atomicMax packed (lk,t) per segment.
// ---------------------------------------------------------------------------
__global__ __launch_bounds__(256, 3) void k3_split(
        const float* __restrict__ P, const float* __restrict__ Qm,
        const f16* __restrict__ W1Ch, const f16* __restrict__ W1Cl,
        const float* __restrict__ b1, const float* __restrict__ Wlk,
        const float* __restrict__ blkp, const float* __restrict__ Wa,
        const float* __restrict__ ba, const int* __restrict__ esrc,
        const int* __restrict__ edst, unsigned long long* __restrict__ keys,
        float* __restrict__ lk_app, float* __restrict__ logits) {
    __shared__ f16 Ah[64 * LP];
    __shared__ f16 Bh[256 * LP], Bl[256 * LP];
    __shared__ float redA[64][5], redB[64][5], redC[64][5];
    __shared__ int s_seg[64], s_dst[64];
    const int tid = threadIdx.x;
    const int wave = tid >> 6, lane = tid & 63;
    const int quad = lane >> 4, l15 = lane & 15;
    const int tbase = blockIdx.x * 64;

    if (tid < 64) {
        int t = tbase + tid;
        int s = 0, d = -1;
        if (t < N_EDGES) { s = esrc[t]; d = edst[t]; }
        else if (t < T_TOT) { s = t - N_EDGES; }
        s_seg[tid] = s;
        s_dst[tid] = d;
    }
    __syncthreads();

    const int arow = tid >> 2, akp = tid & 3;
    const int sA = s_seg[arow], dA = s_dst[arow];
    const float* Prow = P + (size_t)sA * H0D + akp * 8;
    const float* Qrow = Qm + (size_t)(dA >= 0 ? dA : 0) * H0D + akp * 8;
    const bool hasQ = (dA >= 0);

    f32x4 acc[4][4];
#pragma unroll
    for (int i = 0; i < 4; i++)
#pragma unroll
        for (int j = 0; j < 4; j++) acc[i][j] = (f32x4){0.f, 0.f, 0.f, 0.f};

    for (int k0 = 0; k0 < H0D; k0 += 32) {
        float4 a0 = *(const float4*)(Prow + k0);
        float4 a1 = *(const float4*)(Prow + k0 + 4);
        if (hasQ) {
            float4 q0 = *(const float4*)(Qrow + k0);
            float4 q1 = *(const float4*)(Qrow + k0 + 4);
            a0.x += q0.x; a0.y += q0.y; a0.z += q0.z; a0.w += q0.w;
            a1.x += q1.x; a1.y += q1.y; a1.z += q1.z; a1.w += q1.w;
        }
        f16x8 hv;
        hv[0] = (f16)fmaxf(a0.x, 0.f); hv[1] = (f16)fmaxf(a0.y, 0.f);
        hv[2] = (f16)fmaxf(a0.z, 0.f); hv[3] = (f16)fmaxf(a0.w, 0.f);
        hv[4] = (f16)fmaxf(a1.x, 0.f); hv[5] = (f16)fmaxf(a1.y, 0.f);
        hv[6] = (f16)fmaxf(a1.z, 0.f); hv[7] = (f16)fmaxf(a1.w, 0.f);
        const f16* bsh = W1Ch + (size_t)(k0 >> 5) * (256 * 32);
        const f16* bsl = W1Cl + (size_t)(k0 >> 5) * (256 * 32);
        f16x8 bvh[4], bvl[4];
#pragma unroll
        for (int r = 0; r < 4; r++) {
            bvh[r] = *(const f16x8*)(bsh + (size_t)(tid + 256 * r) * 8);
            bvl[r] = *(const f16x8*)(bsl + (size_t)(tid + 256 * r) * 8);
        }
        *(f16x8*)(Ah + arow * LP + akp * 8) = hv;
#pragma unroll
        for (int r = 0; r < 4; r++) {
            int f = tid + 256 * r;
            int n = f >> 2, kb = (f & 3) * 8;
            *(f16x8*)(Bh + n * LP + kb) = bvh[r];
            *(f16x8*)(Bl + n * LP + kb) = bvl[r];
        }
        __syncthreads();

        f16x8 afh[4], bfh[4], bfl[4];
#pragma unroll
        for (int rt = 0; rt < 4; rt++)
            afh[rt] = *(const f16x8*)(Ah + (rt * 16 + l15) * LP + quad * 8);
#pragma unroll
        for (int ct = 0; ct < 4; ct++) {
            bfh[ct] = *(const f16x8*)(Bh + (wave * 64 + ct * 16 + l15) * LP + quad * 8);
            bfl[ct] = *(const f16x8*)(Bl + (wave * 64 + ct * 16 + l15) * LP + quad * 8);
        }
#pragma unroll
        for (int rt = 0; rt < 4; rt++)
#pragma unroll
            for (int ct = 0; ct < 4; ct++) {
                acc[rt][ct] = __builtin_amdgcn_mfma_f32_16x16x32_f16(
                    afh[rt], bfh[ct], acc[rt][ct], 0, 0, 0);
                acc[rt][ct] = __builtin_amdgcn_mfma_f32_16x16x32_f16(
                    afh[rt], bfl[ct], acc[rt][ct], 0, 0, 0);
            }
        __syncthreads();
    }

    // epilogue: h = relu(acc + b1); three 256-dots (lk, logit0, logit1)
    float wl[4], wa0[4], wa1[4], bb[4];
#pragma unroll
    for (int ct = 0; ct < 4; ct++) {
        int n = wave * 64 + ct * 16 + l15;
        wl[ct] = Wlk[n];
        wa0[ct] = Wa[2 * n];
        wa1[ct] = Wa[2 * n + 1];
        bb[ct] = b1[n];
    }
#pragma unroll
    for (int rt = 0; rt < 4; rt++) {
#pragma unroll
        for (int reg = 0; reg < 4; reg++) {
            float plk = 0.f, p0 = 0.f, p1 = 0.f;
#pragma unroll
            for (int ct = 0; ct < 4; ct++) {
                float h = fmaxf(acc[rt][ct][reg] + bb[ct], 0.f);
                plk = fmaf(h, wl[ct], plk);
                p0 = fmaf(h, wa0[ct], p0);
                p1 = fmaf(h, wa1[ct], p1);
            }
#pragma unroll
            for (int off = 8; off >= 1; off >>= 1) {
                plk += __shfl_xor(plk, off);
                p0 += __shfl_xor(p0, off);
                p1 += __shfl_xor(p1, off);
            }
            if (l15 == 0) {
                int row = rt * 16 + quad * 4 + reg;
                redA[row][wave] = plk;
                redB[row][wave] = p0;
                redC[row][wave] = p1;
            }
        }
    }
    __syncthreads();
    if (tid < 64) {
        int t = tbase + tid;
        if (t < T_TOT) {
            float lk = redA[tid][0] + redA[tid][1] + redA[tid][2] + redA[tid][3] + blkp[0];
            float l0 = redB[tid][0] + redB[tid][1] + redB[tid][2] + redB[tid][3] + ba[0];
            float l1 = redC[tid][0] + redC[tid][1] + redC[tid][2] + redC[tid][3] + ba[1];
            lk_app[t] = lk;
            logits[2 * t] = l0;
            logits[2 * t + 1] = l1;
            unsigned long long key =
                ((unsigned long long)f2ord(lk) << 32) | (unsigned int)t;
            atomicMax(keys + s_seg[tid], key);
        }
    }
}

// ---------------------------------------------------------------------------
// K_GA: count candidates within MARGIN_LK of seg best (approx).
// ---------------------------------------------------------------------------
__global__ void k_ga(const float* __restrict__ lk_app,
                     const unsigned long long* __restrict__ keys,
                     const int* __restrict__ esrc, int* __restrict__ seg_cnt) {
    int t = blockIdx.x * 256 + threadIdx.x;
    if (t >= T_TOT) return;
    int seg = (t < N_EDGES) ? esrc[t] : t - N_EDGES;
    float best = ord2f((unsigned int)(keys[seg] >> 32));
    if (lk_app[t] >= best - MARGIN_LK) atomicAdd(seg_cnt + seg, 1);
}

// ---------------------------------------------------------------------------
// K_GB: gather (a) all candidates of lk-tied segments (cnt >= 2),
// (b) approx winners whose logit gap is within MARGIN_L (at-bit at risk).
// Duplicates are harmless (fixup is idempotent).
// ---------------------------------------------------------------------------
__global__ void k_gb(const float* __restrict__ lk_app,
                     const unsigned long long* __restrict__ keys,
                     const int* __restrict__ esrc,
                     const int* __restrict__ seg_cnt,
                     const float* __restrict__ logits,
                     int* __restrict__ list, int* __restrict__ count) {
    int t = blockIdx.x * 256 + threadIdx.x;
    if (t < T_TOT) {
        int seg = (t < N_EDGES) ? esrc[t] : t - N_EDGES;
        if (seg_cnt[seg] >= 2) {
            float best = ord2f((unsigned int)(keys[seg] >> 32));
            if (lk_app[t] >= best - MARGIN_LK) {
                int idx = atomicAdd(count, 1);
                if (idx < LIST_CAP) list[idx] = t;
            }
        }
    }
    if (t < N_NODES) {
        int tw = (int)(keys[t] & 0xFFFFFFFFull);
        float g = fabsf(logits[2 * tw + 1] - logits[2 * tw]);
        if (g < MARGIN_L) {
            int idx = atomicAdd(count, 1);
            if (idx < LIST_CAP) list[idx] = tw;
        }
    }
}

// ---------------------------------------------------------------------------
// K_FIXUP: exact fp32 recompute of lk + logits for listed entries.
// ---------------------------------------------------------------------------
__global__ __launch_bounds__(256, 2) void k_fixup(
        const float* __restrict__ P, const float* __restrict__ Qm,
        const float* __restrict__ W1, const float* __restrict__ b1,
        const float* __restrict__ Wlk, const float* __restrict__ blkp,
        const float* __restrict__ Wa, const float* __restrict__ ba,
        const int* __restrict__ esrc, const int* __restrict__ edst,
        const int* __restrict__ list, const int* __restrict__ count,
        unsigned long long* __restrict__ keys2, float* __restrict__ logits) {
    __shared__ float Al[MT][KB + 4];
    __shared__ float Bl[KB][256];
    __shared__ int s_seg[MT];
    __shared__ int s_dst[MT];
    __shared__ int s_t[MT];
    const int tid = threadIdx.x;
    const int rg = tid >> 5, cg = tid & 31;
    int cnt = *count;
    if (cnt > LIST_CAP) cnt = LIST_CAP;
    const int nch = (cnt + MT - 1) / MT;

    for (int ch = blockIdx.x; ch < nch; ch += gridDim.x) {
        if (tid < MT) {
            int li = ch * MT + tid;
            int t = (li < cnt) ? list[li] : -1;
            int s = 0, d = -1;
            if (t >= 0) {
                if (t < N_EDGES) { s = esrc[t]; d = edst[t]; }
                else { s = t - N_EDGES; }
            }
            s_t[tid] = t;
            s_seg[tid] = s;
            s_dst[tid] = d;
        }
        __syncthreads();

        float acc[8][8];
#pragma unroll
        for (int i = 0; i < 8; i++)
#pragma unroll
            for (int j = 0; j < 8; j++) acc[i][j] = 0.f;

        for (int k0 = 0; k0 < H0D; k0 += KB) {
#pragma unroll
            for (int r = 0; r < 2; r++) {
                int f = tid + 256 * r;
                int m = f >> 3, q = f & 7;
                int s = s_seg[m], d = s_dst[m];
                float4 v = *(const float4*)(P + (size_t)s * H0D + k0 + q * 4);
                if (d >= 0) {
                    float4 w = *(const float4*)(Qm + (size_t)d * H0D + k0 + q * 4);
                    v.x += w.x; v.y += w.y; v.z += w.z; v.w += w.w;
                }
                v.x = fmaxf(v.x, 0.f); v.y = fmaxf(v.y, 0.f);
                v.z = fmaxf(v.z, 0.f); v.w = fmaxf(v.w, 0.f);
                *(float4*)(&Al[m][q * 4]) = v;
            }
#pragma unroll
            for (int r = 0; r < 8; r++) {
                int f = tid + 256 * r;
                int kk = f >> 6, q = f & 63;
                *(float4*)(&Bl[kk][q * 4]) =
                    *(const float4*)(W1 + (size_t)(k0 + kk) * H1D + q * 4);
            }
            __syncthreads();
            for (int kk = 0; kk < KB; kk++) {
                float a[8], b[8];
#pragma unroll
                for (int i = 0; i < 8; i++) a[i] = Al[rg * 8 + i][kk];
#pragma unroll
                for (int j = 0; j < 8; j++) b[j] = Bl[kk][cg + 32 * j];
#pragma unroll
                for (int i = 0; i < 8; i++)
#pragma unroll
                    for (int j = 0; j < 8; j++)
                        acc[i][j] = fmaf(a[i], b[j], acc[i][j]);
            }
            __syncthreads();
        }

        float wl[8], wa0[8], wa1[8], bb1[8];
#pragma unroll
        for (int j = 0; j < 8; j++) {
            int n = cg + 32 * j;
            wl[j] = Wlk[n];
            wa0[j] = Wa[2 * n];
            wa1[j] = Wa[2 * n + 1];
            bb1[j] = b1[n];
        }
#pragma unroll
        for (int i = 0; i < 8; i++) {
            float plk = 0.f, p0 = 0.f, p1 = 0.f;
#pragma unroll
            for (int j = 0; j < 8; j++) {
                float h = fmaxf(acc[i][j] + bb1[j], 0.f);
                plk = fmaf(h, wl[j], plk);
                p0 = fmaf(h, wa0[j], p0);
                p1 = fmaf(h, wa1[j], p1);
            }
#pragma unroll
            for (int off = 16; off >= 1; off >>= 1) {
                plk += __shfl_xor(plk, off);
                p0 += __shfl_xor(p0, off);
                p1 += __shfl_xor(p1, off);
            }
            if (cg == 0) {
                int m = rg * 8 + i;
                int t = s_t[m];
                if (t >= 0) {
                    float lk = plk + blkp[0];
                    logits[2 * t] = p0 + ba[0];
                    logits[2 * t + 1] = p1 + ba[1];
                    unsigned long long key =
                        ((unsigned long long)f2ord(lk) << 32) | (unsigned int)t;
                    atomicMax(keys2 + s_seg[m], key);
                }
            }
        }
        __syncthreads();
    }
}

// ---------------------------------------------------------------------------
// K4: winner per node (exact keys2 for lk-tied segments, else approx keys);
// at-bit from logits (exact where it matters); last-writer claim (+1 coded).
// ---------------------------------------------------------------------------
__global__ void k4_select(const unsigned long long* __restrict__ keys,
                          const unsigned long long* __restrict__ keys2,
                          const int* __restrict__ seg_cnt,
                          const int* __restrict__ edst,
                          const float* __restrict__ logits,
                          int* __restrict__ chosen_arr,
                          int* __restrict__ tgt_writer) {
    int i = blockIdx.x * 256 + threadIdx.x;
    if (i >= N_NODES) return;
    unsigned long long key = keys[i];
    if (seg_cnt[i] >= 2) {
        unsigned long long k2v = keys2[i];
        if (k2v != 0ull) key = k2v;
    }
    int t = (int)(key & 0xFFFFFFFFull);
    int chosen = (t < N_EDGES) ? edst[t] : -1;
    float lg0 = logits[2 * t], lg1 = logits[2 * t + 1];
    int at1 = (lg1 > lg0) ? 1 : 0;   // argmax: tie -> index 0
    int c = (chosen >= 0 && at1) ? chosen : -1;
    chosen_arr[i] = c;
    if (c >= 0) atomicMax(tgt_writer + c, i + 1);   // last-write-wins: max i
}

// ---------------------------------------------------------------------------
// K5: winning writers update rows: out[c] = relu(0.5*(Z[i] + Z[c]))
// ---------------------------------------------------------------------------
__global__ void k5_update(const int* __restrict__ chosen_arr,
                          const int* __restrict__ tgt_writer,
                          const float* __restrict__ Z,
                          float* __restrict__ out) {
    int i = blockIdx.x;
    int c = chosen_arr[i];
    if (c < 0 || tgt_writer[c] != i + 1) return;
    int n = threadIdx.x;
    float z = 0.5f * (Z[(size_t)i * E_DIM + n] + Z[(size_t)c * E_DIM + n]);
    out[(size_t)c * E_DIM + n] = fmaxf(z, 0.f);
}

// ---------------------------------------------------------------------------
extern "C" void kernel_launch(void* const* d_in, const int* in_sizes, int n_in,
                              void* d_out, int out_size, void* d_ws,
                              size_t ws_size, hipStream_t stream) {
    const float* feat = (const float*)d_in[0];
    const float* We   = (const float*)d_in[1];
    const float* be   = (const float*)d_in[2];
    const float* W0   = (const float*)d_in[3];
    const float* b0   = (const float*)d_in[4];
    const float* W1   = (const float*)d_in[5];
    const float* b1   = (const float*)d_in[6];
    const float* Wlk  = (const float*)d_in[7];
    const float* blkp = (const float*)d_in[8];
    const float* Wa   = (const float*)d_in[9];
    const float* ba   = (const float*)d_in[10];
    const int* esrc   = (const int*)d_in[11];
    const int* edst   = (const int*)d_in[12];
    float* out = (float*)d_out;

    char* ws = (char*)d_ws;
    size_t off = 0;
    float* Z  = (float*)(ws + off); off += (size_t)N_NODES * E_DIM * 4;
    float* P  = (float*)(ws + off); off += (size_t)N_NODES * H0D * 4;
    float* Qm = (float*)(ws + off); off += (size_t)N_NODES * H0D * 4;
    // ---- contiguous zero-init region ----
    char* zero_base = ws + off;
    unsigned long long* keys  = (unsigned long long*)(ws + off); off += N_NODES * 8;
    unsigned long long* keys2 = (unsigned long long*)(ws + off); off += N_NODES * 8;
    int* seg_cnt    = (int*)(ws + off); off += N_NODES * 4;
    int* tgt_writer = (int*)(ws + off); off += N_NODES * 4;   // +1 encoding, 0 = none
    int* count      = (int*)(ws + off); off += 128;
    size_t zero_bytes = (size_t)((ws + off) - zero_base);
    // -------------------------------------
    float* logits = (float*)(ws + off); off += (size_t)T_TOT * 2 * 4;
    float* lk_app = (float*)(ws + off); off += (size_t)T_TOT * 4;
    int* list     = (int*)(ws + off); off += (size_t)LIST_CAP * 4;
    int* chosen_arr = (int*)(ws + off); off += N_NODES * 4;
    f16* WeC_h = (f16*)(ws + off); off += (size_t)16 * 256 * 32 * 2;
    f16* WeC_l = (f16*)(ws + off); off += (size_t)16 * 256 * 32 * 2;
    f16* W1C_h = (f16*)(ws + off); off += (size_t)16 * 256 * 32 * 2;
    f16* W1C_l = (f16*)(ws + off); off += (size_t)16 * 256 * 32 * 2;
    f16* W0C_h = (f16*)(ws + off); off += (size_t)32 * 256 * 32 * 2;
    f16* W0C_l = (f16*)(ws + off); off += (size_t)32 * 256 * 32 * 2;

    hipMemsetAsync(zero_base, 0, zero_bytes, stream);

    k_prep_all<<<dim3(64), 256, 0, stream>>>(
        We, W1, W0, WeC_h, WeC_l, W1C_h, W1C_l, W0C_h, W0C_l);
    k1_split<<<dim3((N_NODES + 63) / 64), 256, 0, stream>>>(
        feat, WeC_h, WeC_l, be, Z, out);
    k2_split<<<dim3((N_NODES + 63) / 64, 4), 256, 0, stream>>>(
        out, W0C_h, W0C_l, b0, P, Qm);
    k3_split<<<dim3((T_TOT + 63) / 64), 256, 0, stream>>>(
        P, Qm, W1C_h, W1C_l, b1, Wlk, blkp, Wa, ba, esrc, edst,
        keys, lk_app, logits);
    k_ga<<<dim3((T_TOT + 255) / 256), 256, 0, stream>>>(lk_app, keys, esrc, seg_cnt);
    k_gb<<<dim3((T_TOT + 255) / 256), 256, 0, stream>>>(
        lk_app, keys, esrc, seg_cnt, logits, list, count);
    k_fixup<<<dim3(FIX_BLOCKS), 256, 0, stream>>>(
        P, Qm, W1, b1, Wlk, blkp, Wa, ba, esrc, edst, list, count, keys2, logits);
    k4_select<<<dim3((N_NODES + 255) / 256), 256, 0, stream>>>(
        keys, keys2, seg_cnt, edst, logits, chosen_arr, tgt_writer);
    k5_update<<<dim3(N_NODES), 256, 0, stream>>>(chosen_arr, tgt_writer, Z, out);
}

// Round 5
// 366.710 us; speedup vs baseline: 2.2775x; 1.1773x over previous
//
#include <hip/hip_runtime.h>
#include <stdint.h>

#define N_NODES 10000
#define F_IN    512
#define E_DIM   256
#define H0D     512
#define H1D     256
#define N_EDGES 160000
#define T_TOT   (N_EDGES + N_NODES)   // 170000

#define MT 64
#define KB 32
#define MARGIN_LK 4e-3f
#define MARGIN_L  4e-3f
#define LIST_CAP 20000
#define FIX_BLOCKS 64
#define LP 40                       // padded LDS row stride in f16 (80B, 16B-aligned)

typedef _Float16 f16;
typedef __attribute__((ext_vector_type(8))) _Float16 f16x8;
typedef __attribute__((ext_vector_type(4))) float f32x4;

// monotone map fp32 -> uint32 (order-preserving)
__device__ __forceinline__ unsigned int f2ord(float f) {
    unsigned int u = __float_as_uint(f);
    return (u & 0x80000000u) ? ~u : (u | 0x80000000u);
}
__device__ __forceinline__ float ord2f(unsigned int o) {
    unsigned int u = (o & 0x80000000u) ? (o & 0x7fffffffu) : ~o;
    return __uint_as_float(u);
}

// ---------------------------------------------------------------------------
// K_PREP_ALL: weight matrices -> chunked n-major split-f16 images.
// blocks 0-15: We; 16-31: W1; 32-63: W0 (4 groups x 8 chunks).
//   img[c][n][kk] = split(W[rowoff + c*32 + kk][colbase + n])
// ---------------------------------------------------------------------------
__global__ void k_prep_all(const float* __restrict__ We,
                           const float* __restrict__ W1,
                           const float* __restrict__ W0,
                           f16* __restrict__ WeC_h, f16* __restrict__ WeC_l,
                           f16* __restrict__ W1C_h, f16* __restrict__ W1C_l,
                           f16* __restrict__ W0C_h, f16* __restrict__ W0C_l) {
    int b = blockIdx.x;
    int n = threadIdx.x;
    const float* W;
    int ld, rowoff, colbase, c;
    f16 *dh_base, *dl_base;
    if (b < 16) {
        W = We; ld = E_DIM; rowoff = 0; colbase = 0; c = b;
        dh_base = WeC_h; dl_base = WeC_l;
    } else if (b < 32) {
        W = W1; ld = H1D; rowoff = 0; colbase = 0; c = b - 16;
        dh_base = W1C_h; dl_base = W1C_l;
    } else {
        int g = (b - 32) >> 3; c = (b - 32) & 7;
        rowoff = (g >= 2) ? 256 : 0; colbase = (g & 1) * 256;
        W = W0; ld = H0D;
        dh_base = W0C_h + (size_t)g * 8 * 256 * 32;
        dl_base = W0C_l + (size_t)g * 8 * 256 * 32;
    }
    f16* dh = dh_base + ((size_t)c * 256 + n) * 32;
    f16* dl = dl_base + ((size_t)c * 256 + n) * 32;
    const float* src = W + (size_t)(rowoff + c * 32) * ld + colbase + n;
#pragma unroll
    for (int kk = 0; kk < 32; kk++) {
        float w = src[(size_t)kk * ld];
        f16 h = (f16)w;
        f16 l = (f16)(w - (float)h);
        dh[kk] = h;
        dl[kk] = l;
    }
}

// ---------------------------------------------------------------------------
// K1: Z = feature @ We + be (3-term split-f16, fp32-class);  out = relu(Z)
// ---------------------------------------------------------------------------
__global__ __launch_bounds__(256, 3) void k1_split(
        const float* __restrict__ feat, const f16* __restrict__ Bh_g,
        const f16* __restrict__ Bl_g, const float* __restrict__ be,
        float* __restrict__ Z, float* __restrict__ out) {
    __shared__ f16 Ah[64 * LP], Al_[64 * LP];
    __shared__ f16 Bh[256 * LP], Bl[256 * LP];
    const int tid = threadIdx.x;
    const int wave = tid >> 6, lane = tid & 63;
    const int quad = lane >> 4, l15 = lane & 15;
    const int mbase = blockIdx.x * 64;
    const int arow = tid >> 2, akp = tid & 3;
    const int gm_a = mbase + arow;
    const float* Arow = feat + (size_t)gm_a * F_IN + akp * 8;
    const bool rowok = (gm_a < N_NODES);

    f32x4 acc[4][4];
#pragma unroll
    for (int i = 0; i < 4; i++)
#pragma unroll
        for (int j = 0; j < 4; j++) acc[i][j] = (f32x4){0.f, 0.f, 0.f, 0.f};

    for (int k0 = 0; k0 < F_IN; k0 += 32) {
        float4 a0 = make_float4(0.f, 0.f, 0.f, 0.f), a1 = a0;
        if (rowok) {
            a0 = *(const float4*)(Arow + k0);
            a1 = *(const float4*)(Arow + k0 + 4);
        }
        f16x8 hv, lv;
        float av[8] = {a0.x, a0.y, a0.z, a0.w, a1.x, a1.y, a1.z, a1.w};
#pragma unroll
        for (int q = 0; q < 8; q++) {
            f16 h = (f16)av[q];
            hv[q] = h;
            lv[q] = (f16)(av[q] - (float)h);
        }
        const f16* bsh = Bh_g + (size_t)(k0 >> 5) * (256 * 32);
        const f16* bsl = Bl_g + (size_t)(k0 >> 5) * (256 * 32);
        f16x8 bvh[4], bvl[4];
#pragma unroll
        for (int r = 0; r < 4; r++) {
            bvh[r] = *(const f16x8*)(bsh + (size_t)(tid + 256 * r) * 8);
            bvl[r] = *(const f16x8*)(bsl + (size_t)(tid + 256 * r) * 8);
        }
        *(f16x8*)(Ah + arow * LP + akp * 8) = hv;
        *(f16x8*)(Al_ + arow * LP + akp * 8) = lv;
#pragma unroll
        for (int r = 0; r < 4; r++) {
            int f = tid + 256 * r;
            int n = f >> 2, kb = (f & 3) * 8;
            *(f16x8*)(Bh + n * LP + kb) = bvh[r];
            *(f16x8*)(Bl + n * LP + kb) = bvl[r];
        }
        __syncthreads();

        f16x8 afh[4], afl[4], bfh[4], bfl[4];
#pragma unroll
        for (int rt = 0; rt < 4; rt++) {
            afh[rt] = *(const f16x8*)(Ah + (rt * 16 + l15) * LP + quad * 8);
            afl[rt] = *(const f16x8*)(Al_ + (rt * 16 + l15) * LP + quad * 8);
        }
#pragma unroll
        for (int ct = 0; ct < 4; ct++) {
            bfh[ct] = *(const f16x8*)(Bh + (wave * 64 + ct * 16 + l15) * LP + quad * 8);
            bfl[ct] = *(const f16x8*)(Bl + (wave * 64 + ct * 16 + l15) * LP + quad * 8);
        }
#pragma unroll
        for (int rt = 0; rt < 4; rt++)
#pragma unroll
            for (int ct = 0; ct < 4; ct++) {
                acc[rt][ct] = __builtin_amdgcn_mfma_f32_16x16x32_f16(
                    afh[rt], bfh[ct], acc[rt][ct], 0, 0, 0);
                acc[rt][ct] = __builtin_amdgcn_mfma_f32_16x16x32_f16(
                    afl[rt], bfh[ct], acc[rt][ct], 0, 0, 0);
                acc[rt][ct] = __builtin_amdgcn_mfma_f32_16x16x32_f16(
                    afh[rt], bfl[ct], acc[rt][ct], 0, 0, 0);
            }
        __syncthreads();
    }

#pragma unroll
    for (int ct = 0; ct < 4; ct++) {
        int n = wave * 64 + ct * 16 + l15;
        float bb = be[n];
#pragma unroll
        for (int rt = 0; rt < 4; rt++)
#pragma unroll
            for (int reg = 0; reg < 4; reg++) {
                int gm = mbase + rt * 16 + quad * 4 + reg;
                if (gm < N_NODES) {
                    float z = acc[rt][ct][reg] + bb;
                    Z[(size_t)gm * E_DIM + n] = z;
                    out[(size_t)gm * E_DIM + n] = fmaxf(z, 0.f);
                }
            }
    }
}

// ---------------------------------------------------------------------------
// K2: P' = emb @ W0[0:256,:] + b0 ; Q = emb @ W0[256:512,:]  (3-term exact)
// Also emits f16 copies Pf/Qf for k3's low-precision gather.
// ---------------------------------------------------------------------------
__global__ __launch_bounds__(256, 3) void k2_split(
        const float* __restrict__ emb, const f16* __restrict__ W0Ch,
        const f16* __restrict__ W0Cl, const float* __restrict__ b0,
        float* __restrict__ P, float* __restrict__ Qm,
        f16* __restrict__ Pf, f16* __restrict__ Qf) {
    __shared__ f16 Ah[64 * LP], Al_[64 * LP];
    __shared__ f16 Bh[256 * LP], Bl[256 * LP];
    const int tid = threadIdx.x;
    const int wave = tid >> 6, lane = tid & 63;
    const int quad = lane >> 4, l15 = lane & 15;
    const int mbase = blockIdx.x * 64;
    const int g = blockIdx.y;
    const int isQ = (g >= 2);
    const int colbase = (g & 1) * 256;
    const int arow = tid >> 2, akp = tid & 3;
    const int gm_a = mbase + arow;
    const float* Arow = emb + (size_t)gm_a * E_DIM + akp * 8;
    const bool rowok = (gm_a < N_NODES);
    const f16* Bh_g = W0Ch + (size_t)g * 8 * 256 * 32;
    const f16* Bl_g = W0Cl + (size_t)g * 8 * 256 * 32;

    f32x4 acc[4][4];
#pragma unroll
    for (int i = 0; i < 4; i++)
#pragma unroll
        for (int j = 0; j < 4; j++) acc[i][j] = (f32x4){0.f, 0.f, 0.f, 0.f};

    for (int k0 = 0; k0 < E_DIM; k0 += 32) {
        float4 a0 = make_float4(0.f, 0.f, 0.f, 0.f), a1 = a0;
        if (rowok) {
            a0 = *(const float4*)(Arow + k0);
            a1 = *(const float4*)(Arow + k0 + 4);
        }
        f16x8 hv, lv;
        float av[8] = {a0.x, a0.y, a0.z, a0.w, a1.x, a1.y, a1.z, a1.w};
#pragma unroll
        for (int q = 0; q < 8; q++) {
            f16 h = (f16)av[q];
            hv[q] = h;
            lv[q] = (f16)(av[q] - (float)h);
        }
        const f16* bsh = Bh_g + (size_t)(k0 >> 5) * (256 * 32);
        const f16* bsl = Bl_g + (size_t)(k0 >> 5) * (256 * 32);
        f16x8 bvh[4], bvl[4];
#pragma unroll
        for (int r = 0; r < 4; r++) {
            bvh[r] = *(const f16x8*)(bsh + (size_t)(tid + 256 * r) * 8);
            bvl[r] = *(const f16x8*)(bsl + (size_t)(tid + 256 * r) * 8);
        }
        *(f16x8*)(Ah + arow * LP + akp * 8) = hv;
        *(f16x8*)(Al_ + arow * LP + akp * 8) = lv;
#pragma unroll
        for (int r = 0; r < 4; r++) {
            int f = tid + 256 * r;
            int n = f >> 2, kb = (f & 3) * 8;
            *(f16x8*)(Bh + n * LP + kb) = bvh[r];
            *(f16x8*)(Bl + n * LP + kb) = bvl[r];
        }
        __syncthreads();

        f16x8 afh[4], afl[4], bfh[4], bfl[4];
#pragma unroll
        for (int rt = 0; rt < 4; rt++) {
            afh[rt] = *(const f16x8*)(Ah + (rt * 16 + l15) * LP + quad * 8);
            afl[rt] = *(const f16x8*)(Al_ + (rt * 16 + l15) * LP + quad * 8);
        }
#pragma unroll
        for (int ct = 0; ct < 4; ct++) {
            bfh[ct] = *(const f16x8*)(Bh + (wave * 64 + ct * 16 + l15) * LP + quad * 8);
            bfl[ct] = *(const f16x8*)(Bl + (wave * 64 + ct * 16 + l15) * LP + quad * 8);
        }
#pragma unroll
        for (int rt = 0; rt < 4; rt++)
#pragma unroll
            for (int ct = 0; ct < 4; ct++) {
                acc[rt][ct] = __builtin_amdgcn_mfma_f32_16x16x32_f16(
                    afh[rt], bfh[ct], acc[rt][ct], 0, 0, 0);
                acc[rt][ct] = __builtin_amdgcn_mfma_f32_16x16x32_f16(
                    afl[rt], bfh[ct], acc[rt][ct], 0, 0, 0);
                acc[rt][ct] = __builtin_amdgcn_mfma_f32_16x16x32_f16(
                    afh[rt], bfl[ct], acc[rt][ct], 0, 0, 0);
            }
        __syncthreads();
    }

    float* dst = isQ ? Qm : P;
    f16* dstf = isQ ? Qf : Pf;
#pragma unroll
    for (int ct = 0; ct < 4; ct++) {
        int n = wave * 64 + ct * 16 + l15;
        float bb = isQ ? 0.f : b0[colbase + n];
#pragma unroll
        for (int rt = 0; rt < 4; rt++)
#pragma unroll
            for (int reg = 0; reg < 4; reg++) {
                int gm = mbase + rt * 16 + quad * 4 + reg;
                if (gm < N_NODES) {
                    float v = acc[rt][ct][reg] + bb;
                    dst[(size_t)gm * H0D + colbase + n] = v;
                    dstf[(size_t)gm * H0D + colbase + n] = (f16)v;
                }
            }
    }
}

// ---------------------------------------------------------------------------
// K3 (1-term, f16 gather, pipelined): h1 = relu(Pf[seg]+Qf[dst]) in f16;
// h = relu(h1@W1h+b1); lk + logits (~4e-4-class). atomicMax (lk,t) per seg.
// ---------------------------------------------------------------------------
__global__ __launch_bounds__(256, 3) void k3_f16(
        const f16* __restrict__ Pf, const f16* __restrict__ Qf,
        const f16* __restrict__ W1Bh, const float* __restrict__ b1,
        const float* __restrict__ Wlk, const float* __restrict__ blkp,
        const float* __restrict__ Wa, const float* __restrict__ ba,
        const int* __restrict__ esrc, const int* __restrict__ edst,
        unsigned long long* __restrict__ keys, float* __restrict__ lk_app,
        float* __restrict__ logits) {
    __shared__ f16 Ah[64 * LP];
    __shared__ f16 Bh[256 * LP];
    __shared__ float redA[64][5], redB[64][5], redC[64][5];
    __shared__ int s_seg[64], s_dst[64];
    const int tid = threadIdx.x;
    const int wave = tid >> 6, lane = tid & 63;
    const int quad = lane >> 4, l15 = lane & 15;
    const int tbase = blockIdx.x * 64;

    if (tid < 64) {
        int t = tbase + tid;
        int s = 0, d = -1;
        if (t < N_EDGES) { s = esrc[t]; d = edst[t]; }
        else if (t < T_TOT) { s = t - N_EDGES; }
        s_seg[tid] = s;
        s_dst[tid] = d;
    }
    __syncthreads();

    const int arow = tid >> 2, akp = tid & 3;
    const int sA = s_seg[arow], dA = s_dst[arow];
    const f16* Prow = Pf + (size_t)sA * H0D + akp * 8;
    const f16* Qrow = Qf + (size_t)(dA >= 0 ? dA : 0) * H0D + akp * 8;
    const bool hasQ = (dA >= 0);
    const f16x8 zero8 = (f16x8)(f16)0;

    f32x4 acc[4][4];
#pragma unroll
    for (int i = 0; i < 4; i++)
#pragma unroll
        for (int j = 0; j < 4; j++) acc[i][j] = (f32x4){0.f, 0.f, 0.f, 0.f};

    // prologue: preload chunk 0
    f16x8 pa = *(const f16x8*)(Prow);
    f16x8 qa = hasQ ? *(const f16x8*)(Qrow) : zero8;
    f16x8 bv[4];
#pragma unroll
    for (int r = 0; r < 4; r++)
        bv[r] = *(const f16x8*)(W1Bh + (size_t)(tid + 256 * r) * 8);

    for (int c = 0; c < 16; c++) {
        // stage current chunk
        f16x8 hv;
#pragma unroll
        for (int q = 0; q < 8; q++) {
            f16 s = pa[q] + qa[q];
            hv[q] = (s > (f16)0) ? s : (f16)0;
        }
        *(f16x8*)(Ah + arow * LP + akp * 8) = hv;
#pragma unroll
        for (int r = 0; r < 4; r++) {
            int f = tid + 256 * r;
            int n = f >> 2, kb = (f & 3) * 8;
            *(f16x8*)(Bh + n * LP + kb) = bv[r];
        }
        __syncthreads();

        // prefetch next chunk (consumed after the MFMA phase)
        if (c + 1 < 16) {
            pa = *(const f16x8*)(Prow + (c + 1) * 32);
            qa = hasQ ? *(const f16x8*)(Qrow + (c + 1) * 32) : zero8;
            const f16* bsrc = W1Bh + (size_t)(c + 1) * (256 * 32);
#pragma unroll
            for (int r = 0; r < 4; r++)
                bv[r] = *(const f16x8*)(bsrc + (size_t)(tid + 256 * r) * 8);
        }

        f16x8 af[4], bf[4];
#pragma unroll
        for (int rt = 0; rt < 4; rt++)
            af[rt] = *(const f16x8*)(Ah + (rt * 16 + l15) * LP + quad * 8);
#pragma unroll
        for (int ct = 0; ct < 4; ct++)
            bf[ct] = *(const f16x8*)(Bh + (wave * 64 + ct * 16 + l15) * LP + quad * 8);
#pragma unroll
        for (int rt = 0; rt < 4; rt++)
#pragma unroll
            for (int ct = 0; ct < 4; ct++)
                acc[rt][ct] = __builtin_amdgcn_mfma_f32_16x16x32_f16(
                    af[rt], bf[ct], acc[rt][ct], 0, 0, 0);
        __syncthreads();
    }

    // epilogue: h = relu(acc + b1); three 256-dots (lk, logit0, logit1)
    float wl[4], wa0[4], wa1[4], bb[4];
#pragma unroll
    for (int ct = 0; ct < 4; ct++) {
        int n = wave * 64 + ct * 16 + l15;
        wl[ct] = Wlk[n];
        wa0[ct] = Wa[2 * n];
        wa1[ct] = Wa[2 * n + 1];
        bb[ct] = b1[n];
    }
#pragma unroll
    for (int rt = 0; rt < 4; rt++) {
#pragma unroll
        for (int reg = 0; reg < 4; reg++) {
            float plk = 0.f, p0 = 0.f, p1 = 0.f;
#pragma unroll
            for (int ct = 0; ct < 4; ct++) {
                float h = fmaxf(acc[rt][ct][reg] + bb[ct], 0.f);
                plk = fmaf(h, wl[ct], plk);
                p0 = fmaf(h, wa0[ct], p0);
                p1 = fmaf(h, wa1[ct], p1);
            }
#pragma unroll
            for (int off = 8; off >= 1; off >>= 1) {
                plk += __shfl_xor(plk, off);
                p0 += __shfl_xor(p0, off);
                p1 += __shfl_xor(p1, off);
            }
            if (l15 == 0) {
                int row = rt * 16 + quad * 4 + reg;
                redA[row][wave] = plk;
                redB[row][wave] = p0;
                redC[row][wave] = p1;
            }
        }
    }
    __syncthreads();
    if (tid < 64) {
        int t = tbase + tid;
        if (t < T_TOT) {
            float lk = redA[tid][0] + redA[tid][1] + redA[tid][2] + redA[tid][3] + blkp[0];
            float l0 = redB[tid][0] + redB[tid][1] + redB[tid][2] + redB[tid][3] + ba[0];
            float l1 = redC[tid][0] + redC[tid][1] + redC[tid][2] + redC[tid][3] + ba[1];
            lk_app[t] = lk;
            logits[2 * t] = l0;
            logits[2 * t + 1] = l1;
            unsigned long long key =
                ((unsigned long long)f2ord(lk) << 32) | (unsigned int)t;
            atomicMax(keys + s_seg[tid], key);
        }
    }
}

// ---------------------------------------------------------------------------
// K_GB: gather (a) challengers within MARGIN_LK of their segment best plus the
// segment's approx winner; (b) approx winners whose logit gap < MARGIN_L.
// Duplicates are harmless (fixup idempotent).
// ---------------------------------------------------------------------------
__global__ void k_gb(const float* __restrict__ lk_app,
                     const unsigned long long* __restrict__ keys,
                     const int* __restrict__ esrc,
                     const float* __restrict__ logits,
                     int* __restrict__ list, int* __restrict__ count) {
    int t = blockIdx.x * 256 + threadIdx.x;
    if (t < T_TOT) {
        int seg = (t < N_EDGES) ? esrc[t] : t - N_EDGES;
        unsigned long long k = keys[seg];
        int tw = (int)(k & 0xFFFFFFFFull);
        if (t != tw) {
            float best = ord2f((unsigned int)(k >> 32));
            if (lk_app[t] >= best - MARGIN_LK) {
                int idx = atomicAdd(count, 2);
                if (idx + 1 < LIST_CAP) { list[idx] = t; list[idx + 1] = tw; }
            }
        }
    }
    if (t < N_NODES) {
        int tw = (int)(keys[t] & 0xFFFFFFFFull);
        float g = fabsf(logits[2 * tw + 1] - logits[2 * tw]);
        if (g < MARGIN_L) {
            int idx = atomicAdd(count, 1);
            if (idx < LIST_CAP) list[idx] = tw;
        }
    }
}

// ---------------------------------------------------------------------------
// K_FIXUP: exact fp32 recompute of lk + logits for listed entries.
// ---------------------------------------------------------------------------
__global__ __launch_bounds__(256, 2) void k_fixup(
        const float* __restrict__ P, const float* __restrict__ Qm,
        const float* __restrict__ W1, const float* __restrict__ b1,
        const float* __restrict__ Wlk, const float* __restrict__ blkp,
        const float* __restrict__ Wa, const float* __restrict__ ba,
        const int* __restrict__ esrc, const int* __restrict__ edst,
        const int* __restrict__ list, const int* __restrict__ count,
        unsigned long long* __restrict__ keys2, float* __restrict__ logits) {
    __shared__ float Al[MT][KB + 4];
    __shared__ float Bl[KB][256];
    __shared__ int s_seg[MT];
    __shared__ int s_dst[MT];
    __shared__ int s_t[MT];
    const int tid = threadIdx.x;
    const int rg = tid >> 5, cg = tid & 31;
    int cnt = *count;
    if (cnt > LIST_CAP) cnt = LIST_CAP;
    const int nch = (cnt + MT - 1) / MT;

    for (int ch = blockIdx.x; ch < nch; ch += gridDim.x) {
        if (tid < MT) {
            int li = ch * MT + tid;
            int t = (li < cnt) ? list[li] : -1;
            int s = 0, d = -1;
            if (t >= 0) {
                if (t < N_EDGES) { s = esrc[t]; d = edst[t]; }
                else { s = t - N_EDGES; }
            }
            s_t[tid] = t;
            s_seg[tid] = s;
            s_dst[tid] = d;
        }
        __syncthreads();

        float acc[8][8];
#pragma unroll
        for (int i = 0; i < 8; i++)
#pragma unroll
            for (int j = 0; j < 8; j++) acc[i][j] = 0.f;

        for (int k0 = 0; k0 < H0D; k0 += KB) {
#pragma unroll
            for (int r = 0; r < 2; r++) {
                int f = tid + 256 * r;
                int m = f >> 3, q = f & 7;
                int s = s_seg[m], d = s_dst[m];
                float4 v = *(const float4*)(P + (size_t)s * H0D + k0 + q * 4);
                if (d >= 0) {
                    float4 w = *(const float4*)(Qm + (size_t)d * H0D + k0 + q * 4);
                    v.x += w.x; v.y += w.y; v.z += w.z; v.w += w.w;
                }
                v.x = fmaxf(v.x, 0.f); v.y = fmaxf(v.y, 0.f);
                v.z = fmaxf(v.z, 0.f); v.w = fmaxf(v.w, 0.f);
                *(float4*)(&Al[m][q * 4]) = v;
            }
#pragma unroll
            for (int r = 0; r < 8; r++) {
                int f = tid + 256 * r;
                int kk = f >> 6, q = f & 63;
                *(float4*)(&Bl[kk][q * 4]) =
                    *(const float4*)(W1 + (size_t)(k0 + kk) * H1D + q * 4);
            }
            __syncthreads();
            for (int kk = 0; kk < KB; kk++) {
                float a[8], b[8];
#pragma unroll
                for (int i = 0; i < 8; i++) a[i] = Al[rg * 8 + i][kk];
#pragma unroll
                for (int j = 0; j < 8; j++) b[j] = Bl[kk][cg + 32 * j];
#pragma unroll
                for (int i = 0; i < 8; i++)
#pragma unroll
                    for (int j = 0; j < 8; j++)
                        acc[i][j] = fmaf(a[i], b[j], acc[i][j]);
            }
            __syncthreads();
        }

        float wl[8], wa0[8], wa1[8], bb1[8];
#pragma unroll
        for (int j = 0; j < 8; j++) {
            int n = cg + 32 * j;
            wl[j] = Wlk[n];
            wa0[j] = Wa[2 * n];
            wa1[j] = Wa[2 * n + 1];
            bb1[j] = b1[n];
        }
#pragma unroll
        for (int i = 0; i < 8; i++) {
            float plk = 0.f, p0 = 0.f, p1 = 0.f;
#pragma unroll
            for (int j = 0; j < 8; j++) {
                float h = fmaxf(acc[i][j] + bb1[j], 0.f);
                plk = fmaf(h, wl[j], plk);
                p0 = fmaf(h, wa0[j], p0);
                p1 = fmaf(h, wa1[j], p1);
            }
#pragma unroll
            for (int off = 16; off >= 1; off >>= 1) {
                plk += __shfl_xor(plk, off);
                p0 += __shfl_xor(p0, off);
                p1 += __shfl_xor(p1, off);
            }
            if (cg == 0) {
                int m = rg * 8 + i;
                int t = s_t[m];
                if (t >= 0) {
                    float lk = plk + blkp[0];
                    logits[2 * t] = p0 + ba[0];
                    logits[2 * t + 1] = p1 + ba[1];
                    unsigned long long key =
                        ((unsigned long long)f2ord(lk) << 32) | (unsigned int)t;
                    atomicMax(keys2 + s_seg[m], key);
                }
            }
        }
        __syncthreads();
    }
}

// ---------------------------------------------------------------------------
// K4: winner per node (keys2 if any exact candidates, else approx keys);
// at-bit from logits (exact where at risk); last-writer claim (+1 coded).
// ---------------------------------------------------------------------------
__global__ void k4_select(const unsigned long long* __restrict__ keys,
                          const unsigned long long* __restrict__ keys2,
                          const int* __restrict__ edst,
                          const float* __restrict__ logits,
                          int* __restrict__ chosen_arr,
                          int* __restrict__ tgt_writer) {
    int i = blockIdx.x * 256 + threadIdx.x;
    if (i >= N_NODES) return;
    unsigned long long key = keys[i];
    unsigned long long k2v = keys2[i];
    if (k2v != 0ull) key = k2v;
    int t = (int)(key & 0xFFFFFFFFull);
    int chosen = (t < N_EDGES) ? edst[t] : -1;
    float lg0 = logits[2 * t], lg1 = logits[2 * t + 1];
    int at1 = (lg1 > lg0) ? 1 : 0;   // argmax: tie -> index 0
    int c = (chosen >= 0 && at1) ? chosen : -1;
    chosen_arr[i] = c;
    if (c >= 0) atomicMax(tgt_writer + c, i + 1);   // last-write-wins: max i
}

// ---------------------------------------------------------------------------
// K5: winning writers update rows: out[c] = relu(0.5*(Z[i] + Z[c]))
// ---------------------------------------------------------------------------
__global__ void k5_update(const int* __restrict__ chosen_arr,
                          const int* __restrict__ tgt_writer,
                          const float* __restrict__ Z,
                          float* __restrict__ out) {
    int i = blockIdx.x;
    int c = chosen_arr[i];
    if (c < 0 || tgt_writer[c] != i + 1) return;
    int n = threadIdx.x;
    float z = 0.5f * (Z[(size_t)i * E_DIM + n] + Z[(size_t)c * E_DIM + n]);
    out[(size_t)c * E_DIM + n] = fmaxf(z, 0.f);
}

// ---------------------------------------------------------------------------
extern "C" void kernel_launch(void* const* d_in, const int* in_sizes, int n_in,
                              void* d_out, int out_size, void* d_ws,
                              size_t ws_size, hipStream_t stream) {
    const float* feat = (const float*)d_in[0];
    const float* We   = (const float*)d_in[1];
    const float* be   = (const float*)d_in[2];
    const float* W0   = (const float*)d_in[3];
    const float* b0   = (const float*)d_in[4];
    const float* W1   = (const float*)d_in[5];
    const float* b1   = (const float*)d_in[6];
    const float* Wlk  = (const float*)d_in[7];
    const float* blkp = (const float*)d_in[8];
    const float* Wa   = (const float*)d_in[9];
    const float* ba   = (const float*)d_in[10];
    const int* esrc   = (const int*)d_in[11];
    const int* edst   = (const int*)d_in[12];
    float* out = (float*)d_out;

    char* ws = (char*)d_ws;
    size_t off = 0;
    float* Z  = (float*)(ws + off); off += (size_t)N_NODES * E_DIM * 4;
    float* P  = (float*)(ws + off); off += (size_t)N_NODES * H0D * 4;
    float* Qm = (float*)(ws + off); off += (size_t)N_NODES * H0D * 4;
    f16* Pf   = (f16*)(ws + off);   off += (size_t)N_NODES * H0D * 2;
    f16* Qf   = (f16*)(ws + off);   off += (size_t)N_NODES * H0D * 2;
    // ---- contiguous zero-init region ----
    char* zero_base = ws + off;
    unsigned long long* keys  = (unsigned long long*)(ws + off); off += N_NODES * 8;
    unsigned long long* keys2 = (unsigned long long*)(ws + off); off += N_NODES * 8;
    int* tgt_writer = (int*)(ws + off); off += N_NODES * 4;   // +1 encoding, 0 = none
    int* count      = (int*)(ws + off); off += 128;
    size_t zero_bytes = (size_t)((ws + off) - zero_base);
    // -------------------------------------
    float* logits = (float*)(ws + off); off += (size_t)T_TOT * 2 * 4;
    float* lk_app = (float*)(ws + off); off += (size_t)T_TOT * 4;
    int* list     = (int*)(ws + off); off += (size_t)LIST_CAP * 4;
    int* chosen_arr = (int*)(ws + off); off += N_NODES * 4;
    f16* WeC_h = (f16*)(ws + off); off += (size_t)16 * 256 * 32 * 2;
    f16* WeC_l = (f16*)(ws + off); off += (size_t)16 * 256 * 32 * 2;
    f16* W1C_h = (f16*)(ws + off); off += (size_t)16 * 256 * 32 * 2;
    f16* W1C_l = (f16*)(ws + off); off += (size_t)16 * 256 * 32 * 2;
    f16* W0C_h = (f16*)(ws + off); off += (size_t)32 * 256 * 32 * 2;
    f16* W0C_l = (f16*)(ws + off); off += (size_t)32 * 256 * 32 * 2;

    hipMemsetAsync(zero_base, 0, zero_bytes, stream);

    k_prep_all<<<dim3(64), 256, 0, stream>>>(
        We, W1, W0, WeC_h, WeC_l, W1C_h, W1C_l, W0C_h, W0C_l);
    k1_split<<<dim3((N_NODES + 63) / 64), 256, 0, stream>>>(
        feat, WeC_h, WeC_l, be, Z, out);
    k2_split<<<dim3((N_NODES + 63) / 64, 4), 256, 0, stream>>>(
        out, W0C_h, W0C_l, b0, P, Qm, Pf, Qf);
    k3_f16<<<dim3((T_TOT + 63) / 64), 256, 0, stream>>>(
        Pf, Qf, W1C_h, b1, Wlk, blkp, Wa, ba, esrc, edst,
        keys, lk_app, logits);
    k_gb<<<dim3((T_TOT + 255) / 256), 256, 0, stream>>>(
        lk_app, keys, esrc, logits, list, count);
    k_fixup<<<dim3(FIX_BLOCKS), 256, 0, stream>>>(
        P, Qm, W1, b1, Wlk, blkp, Wa, ba, esrc, edst, list, count, keys2, logits);
    k4_select<<<dim3((N_NODES + 255) / 256), 256, 0, stream>>>(
        keys, keys2, edst, logits, chosen_arr, tgt_writer);
    k5_update<<<dim3(N_NODES), 256, 0, stream>>>(chosen_arr, tgt_writer, Z, out);
}

// Round 6
// 330.143 us; speedup vs baseline: 2.5298x; 1.1108x over previous
//
#include <hip/hip_runtime.h>
#include <stdint.h>

#define N_NODES 10000
#define F_IN    512
#define E_DIM   256
#define H0D     512
#define H1D     256
#define N_EDGES 160000
#define T_TOT   (N_EDGES + N_NODES)   // 170000

#define MT 64
#define KB 32
#define MARGIN_LK 4e-3f
#define MARGIN_L  4e-3f
#define LIST_CAP 20000
#define FIX_GRID 1024
#define LP 40                       // padded LDS row stride in f16 (80B, 16B-aligned)

typedef _Float16 f16;
typedef __attribute__((ext_vector_type(8))) _Float16 f16x8;
typedef __attribute__((ext_vector_type(4))) float f32x4;

// monotone map fp32 -> uint32 (order-preserving)
__device__ __forceinline__ unsigned int f2ord(float f) {
    unsigned int u = __float_as_uint(f);
    return (u & 0x80000000u) ? ~u : (u | 0x80000000u);
}
__device__ __forceinline__ float ord2f(unsigned int o) {
    unsigned int u = (o & 0x80000000u) ? (o & 0x7fffffffu) : ~o;
    return __uint_as_float(u);
}

// ---------------------------------------------------------------------------
// K_PREP_ALL: weight matrices -> chunked n-major split-f16 images + fp32 W1T.
// blocks 0-15: We; 16-31: W1; 32-63: W0 (4 groups x 8 chunks);
// blocks 64-95: W1T[j][k] = W1[k][j]  (fp32 transpose for the exact fixup).
// ---------------------------------------------------------------------------
__global__ void k_prep_all(const float* __restrict__ We,
                           const float* __restrict__ W1,
                           const float* __restrict__ W0,
                           f16* __restrict__ WeC_h, f16* __restrict__ WeC_l,
                           f16* __restrict__ W1C_h, f16* __restrict__ W1C_l,
                           f16* __restrict__ W0C_h, f16* __restrict__ W0C_l,
                           float* __restrict__ W1T) {
    int b = blockIdx.x;
    int n = threadIdx.x;
    if (b >= 64) {
        // transpose W1 [512][256] -> W1T [256][512]
        int j = (b - 64) * 8 + (n >> 5);
        int k0 = (n & 31) * 16;
#pragma unroll
        for (int kk = 0; kk < 16; kk++)
            W1T[(size_t)j * 512 + k0 + kk] = W1[(size_t)(k0 + kk) * H1D + j];
        return;
    }
    const float* W;
    int ld, rowoff, colbase, c;
    f16 *dh_base, *dl_base;
    if (b < 16) {
        W = We; ld = E_DIM; rowoff = 0; colbase = 0; c = b;
        dh_base = WeC_h; dl_base = WeC_l;
    } else if (b < 32) {
        W = W1; ld = H1D; rowoff = 0; colbase = 0; c = b - 16;
        dh_base = W1C_h; dl_base = W1C_l;
    } else {
        int g = (b - 32) >> 3; c = (b - 32) & 7;
        rowoff = (g >= 2) ? 256 : 0; colbase = (g & 1) * 256;
        W = W0; ld = H0D;
        dh_base = W0C_h + (size_t)g * 8 * 256 * 32;
        dl_base = W0C_l + (size_t)g * 8 * 256 * 32;
    }
    f16* dh = dh_base + ((size_t)c * 256 + n) * 32;
    f16* dl = dl_base + ((size_t)c * 256 + n) * 32;
    const float* src = W + (size_t)(rowoff + c * 32) * ld + colbase + n;
#pragma unroll
    for (int kk = 0; kk < 32; kk++) {
        float w = src[(size_t)kk * ld];
        f16 h = (f16)w;
        f16 l = (f16)(w - (float)h);
        dh[kk] = h;
        dl[kk] = l;
    }
}

// ---------------------------------------------------------------------------
// K1: Z = feature @ We + be (3-term split-f16, fp32-class);  out = relu(Z)
// ---------------------------------------------------------------------------
__global__ __launch_bounds__(256, 3) void k1_split(
        const float* __restrict__ feat, const f16* __restrict__ Bh_g,
        const f16* __restrict__ Bl_g, const float* __restrict__ be,
        float* __restrict__ Z, float* __restrict__ out) {
    __shared__ f16 Ah[64 * LP], Al_[64 * LP];
    __shared__ f16 Bh[256 * LP], Bl[256 * LP];
    const int tid = threadIdx.x;
    const int wave = tid >> 6, lane = tid & 63;
    const int quad = lane >> 4, l15 = lane & 15;
    const int mbase = blockIdx.x * 64;
    const int arow = tid >> 2, akp = tid & 3;
    const int gm_a = mbase + arow;
    const float* Arow = feat + (size_t)gm_a * F_IN + akp * 8;
    const bool rowok = (gm_a < N_NODES);

    f32x4 acc[4][4];
#pragma unroll
    for (int i = 0; i < 4; i++)
#pragma unroll
        for (int j = 0; j < 4; j++) acc[i][j] = (f32x4){0.f, 0.f, 0.f, 0.f};

    for (int k0 = 0; k0 < F_IN; k0 += 32) {
        float4 a0 = make_float4(0.f, 0.f, 0.f, 0.f), a1 = a0;
        if (rowok) {
            a0 = *(const float4*)(Arow + k0);
            a1 = *(const float4*)(Arow + k0 + 4);
        }
        f16x8 hv, lv;
        float av[8] = {a0.x, a0.y, a0.z, a0.w, a1.x, a1.y, a1.z, a1.w};
#pragma unroll
        for (int q = 0; q < 8; q++) {
            f16 h = (f16)av[q];
            hv[q] = h;
            lv[q] = (f16)(av[q] - (float)h);
        }
        const f16* bsh = Bh_g + (size_t)(k0 >> 5) * (256 * 32);
        const f16* bsl = Bl_g + (size_t)(k0 >> 5) * (256 * 32);
        f16x8 bvh[4], bvl[4];
#pragma unroll
        for (int r = 0; r < 4; r++) {
            bvh[r] = *(const f16x8*)(bsh + (size_t)(tid + 256 * r) * 8);
            bvl[r] = *(const f16x8*)(bsl + (size_t)(tid + 256 * r) * 8);
        }
        *(f16x8*)(Ah + arow * LP + akp * 8) = hv;
        *(f16x8*)(Al_ + arow * LP + akp * 8) = lv;
#pragma unroll
        for (int r = 0; r < 4; r++) {
            int f = tid + 256 * r;
            int n = f >> 2, kb = (f & 3) * 8;
            *(f16x8*)(Bh + n * LP + kb) = bvh[r];
            *(f16x8*)(Bl + n * LP + kb) = bvl[r];
        }
        __syncthreads();

        f16x8 afh[4], afl[4], bfh[4], bfl[4];
#pragma unroll
        for (int rt = 0; rt < 4; rt++) {
            afh[rt] = *(const f16x8*)(Ah + (rt * 16 + l15) * LP + quad * 8);
            afl[rt] = *(const f16x8*)(Al_ + (rt * 16 + l15) * LP + quad * 8);
        }
#pragma unroll
        for (int ct = 0; ct < 4; ct++) {
            bfh[ct] = *(const f16x8*)(Bh + (wave * 64 + ct * 16 + l15) * LP + quad * 8);
            bfl[ct] = *(const f16x8*)(Bl + (wave * 64 + ct * 16 + l15) * LP + quad * 8);
        }
#pragma unroll
        for (int rt = 0; rt < 4; rt++)
#pragma unroll
            for (int ct = 0; ct < 4; ct++) {
                acc[rt][ct] = __builtin_amdgcn_mfma_f32_16x16x32_f16(
                    afh[rt], bfh[ct], acc[rt][ct], 0, 0, 0);
                acc[rt][ct] = __builtin_amdgcn_mfma_f32_16x16x32_f16(
                    afl[rt], bfh[ct], acc[rt][ct], 0, 0, 0);
                acc[rt][ct] = __builtin_amdgcn_mfma_f32_16x16x32_f16(
                    afh[rt], bfl[ct], acc[rt][ct], 0, 0, 0);
            }
        __syncthreads();
    }

#pragma unroll
    for (int ct = 0; ct < 4; ct++) {
        int n = wave * 64 + ct * 16 + l15;
        float bb = be[n];
#pragma unroll
        for (int rt = 0; rt < 4; rt++)
#pragma unroll
            for (int reg = 0; reg < 4; reg++) {
                int gm = mbase + rt * 16 + quad * 4 + reg;
                if (gm < N_NODES) {
                    float z = acc[rt][ct][reg] + bb;
                    Z[(size_t)gm * E_DIM + n] = z;
                    out[(size_t)gm * E_DIM + n] = fmaxf(z, 0.f);
                }
            }
    }
}

// ---------------------------------------------------------------------------
// K2: P' = emb @ W0[0:256,:] + b0 ; Q = emb @ W0[256:512,:]  (3-term exact)
// Also emits f16 copies Pf/Qf for k3's low-precision gather.
// ---------------------------------------------------------------------------
__global__ __launch_bounds__(256, 3) void k2_split(
        const float* __restrict__ emb, const f16* __restrict__ W0Ch,
        const f16* __restrict__ W0Cl, const float* __restrict__ b0,
        float* __restrict__ P, float* __restrict__ Qm,
        f16* __restrict__ Pf, f16* __restrict__ Qf) {
    __shared__ f16 Ah[64 * LP], Al_[64 * LP];
    __shared__ f16 Bh[256 * LP], Bl[256 * LP];
    const int tid = threadIdx.x;
    const int wave = tid >> 6, lane = tid & 63;
    const int quad = lane >> 4, l15 = lane & 15;
    const int mbase = blockIdx.x * 64;
    const int g = blockIdx.y;
    const int isQ = (g >= 2);
    const int colbase = (g & 1) * 256;
    const int arow = tid >> 2, akp = tid & 3;
    const int gm_a = mbase + arow;
    const float* Arow = emb + (size_t)gm_a * E_DIM + akp * 8;
    const bool rowok = (gm_a < N_NODES);
    const f16* Bh_g = W0Ch + (size_t)g * 8 * 256 * 32;
    const f16* Bl_g = W0Cl + (size_t)g * 8 * 256 * 32;

    f32x4 acc[4][4];
#pragma unroll
    for (int i = 0; i < 4; i++)
#pragma unroll
        for (int j = 0; j < 4; j++) acc[i][j] = (f32x4){0.f, 0.f, 0.f, 0.f};

    for (int k0 = 0; k0 < E_DIM; k0 += 32) {
        float4 a0 = make_float4(0.f, 0.f, 0.f, 0.f), a1 = a0;
        if (rowok) {
            a0 = *(const float4*)(Arow + k0);
            a1 = *(const float4*)(Arow + k0 + 4);
        }
        f16x8 hv, lv;
        float av[8] = {a0.x, a0.y, a0.z, a0.w, a1.x, a1.y, a1.z, a1.w};
#pragma unroll
        for (int q = 0; q < 8; q++) {
            f16 h = (f16)av[q];
            hv[q] = h;
            lv[q] = (f16)(av[q] - (float)h);
        }
        const f16* bsh = Bh_g + (size_t)(k0 >> 5) * (256 * 32);
        const f16* bsl = Bl_g + (size_t)(k0 >> 5) * (256 * 32);
        f16x8 bvh[4], bvl[4];
#pragma unroll
        for (int r = 0; r < 4; r++) {
            bvh[r] = *(const f16x8*)(bsh + (size_t)(tid + 256 * r) * 8);
            bvl[r] = *(const f16x8*)(bsl + (size_t)(tid + 256 * r) * 8);
        }
        *(f16x8*)(Ah + arow * LP + akp * 8) = hv;
        *(f16x8*)(Al_ + arow * LP + akp * 8) = lv;
#pragma unroll
        for (int r = 0; r < 4; r++) {
            int f = tid + 256 * r;
            int n = f >> 2, kb = (f & 3) * 8;
            *(f16x8*)(Bh + n * LP + kb) = bvh[r];
            *(f16x8*)(Bl + n * LP + kb) = bvl[r];
        }
        __syncthreads();

        f16x8 afh[4], afl[4], bfh[4], bfl[4];
#pragma unroll
        for (int rt = 0; rt < 4; rt++) {
            afh[rt] = *(const f16x8*)(Ah + (rt * 16 + l15) * LP + quad * 8);
            afl[rt] = *(const f16x8*)(Al_ + (rt * 16 + l15) * LP + quad * 8);
        }
#pragma unroll
        for (int ct = 0; ct < 4; ct++) {
            bfh[ct] = *(const f16x8*)(Bh + (wave * 64 + ct * 16 + l15) * LP + quad * 8);
            bfl[ct] = *(const f16x8*)(Bl + (wave * 64 + ct * 16 + l15) * LP + quad * 8);
        }
#pragma unroll
        for (int rt = 0; rt < 4; rt++)
#pragma unroll
            for (int ct = 0; ct < 4; ct++) {
                acc[rt][ct] = __builtin_amdgcn_mfma_f32_16x16x32_f16(
                    afh[rt], bfh[ct], acc[rt][ct], 0, 0, 0);
                acc[rt][ct] = __builtin_amdgcn_mfma_f32_16x16x32_f16(
                    afl[rt], bfh[ct], acc[rt][ct], 0, 0, 0);
                acc[rt][ct] = __builtin_amdgcn_mfma_f32_16x16x32_f16(
                    afh[rt], bfl[ct], acc[rt][ct], 0, 0, 0);
            }
        __syncthreads();
    }

    float* dst = isQ ? Qm : P;
    f16* dstf = isQ ? Qf : Pf;
#pragma unroll
    for (int ct = 0; ct < 4; ct++) {
        int n = wave * 64 + ct * 16 + l15;
        float bb = isQ ? 0.f : b0[colbase + n];
#pragma unroll
        for (int rt = 0; rt < 4; rt++)
#pragma unroll
            for (int reg = 0; reg < 4; reg++) {
                int gm = mbase + rt * 16 + quad * 4 + reg;
                if (gm < N_NODES) {
                    float v = acc[rt][ct][reg] + bb;
                    dst[(size_t)gm * H0D + colbase + n] = v;
                    dstf[(size_t)gm * H0D + colbase + n] = (f16)v;
                }
            }
    }
}

// ---------------------------------------------------------------------------
// K3 (1-term, f16 gather, pipelined): h1 = relu(Pf[seg]+Qf[dst]) in f16;
// h = relu(h1@W1h+b1); lk + logits (~4e-4-class). atomicMax (lk,t) per seg.
// ---------------------------------------------------------------------------
__global__ __launch_bounds__(256, 3) void k3_f16(
        const f16* __restrict__ Pf, const f16* __restrict__ Qf,
        const f16* __restrict__ W1Bh, const float* __restrict__ b1,
        const float* __restrict__ Wlk, const float* __restrict__ blkp,
        const float* __restrict__ Wa, const float* __restrict__ ba,
        const int* __restrict__ esrc, const int* __restrict__ edst,
        unsigned long long* __restrict__ keys, float* __restrict__ lk_app,
        float* __restrict__ logits) {
    __shared__ f16 Ah[64 * LP];
    __shared__ f16 Bh[256 * LP];
    __shared__ float redA[64][5], redB[64][5], redC[64][5];
    __shared__ int s_seg[64], s_dst[64];
    const int tid = threadIdx.x;
    const int wave = tid >> 6, lane = tid & 63;
    const int quad = lane >> 4, l15 = lane & 15;
    const int tbase = blockIdx.x * 64;

    if (tid < 64) {
        int t = tbase + tid;
        int s = 0, d = -1;
        if (t < N_EDGES) { s = esrc[t]; d = edst[t]; }
        else if (t < T_TOT) { s = t - N_EDGES; }
        s_seg[tid] = s;
        s_dst[tid] = d;
    }
    __syncthreads();

    const int arow = tid >> 2, akp = tid & 3;
    const int sA = s_seg[arow], dA = s_dst[arow];
    const f16* Prow = Pf + (size_t)sA * H0D + akp * 8;
    const f16* Qrow = Qf + (size_t)(dA >= 0 ? dA : 0) * H0D + akp * 8;
    const bool hasQ = (dA >= 0);
    const f16x8 zero8 = (f16x8)(f16)0;

    f32x4 acc[4][4];
#pragma unroll
    for (int i = 0; i < 4; i++)
#pragma unroll
        for (int j = 0; j < 4; j++) acc[i][j] = (f32x4){0.f, 0.f, 0.f, 0.f};

    // prologue: preload chunk 0
    f16x8 pa = *(const f16x8*)(Prow);
    f16x8 qa = hasQ ? *(const f16x8*)(Qrow) : zero8;
    f16x8 bv[4];
#pragma unroll
    for (int r = 0; r < 4; r++)
        bv[r] = *(const f16x8*)(W1Bh + (size_t)(tid + 256 * r) * 8);

    for (int c = 0; c < 16; c++) {
        // stage current chunk
        f16x8 hv;
#pragma unroll
        for (int q = 0; q < 8; q++) {
            f16 s = pa[q] + qa[q];
            hv[q] = (s > (f16)0) ? s : (f16)0;
        }
        *(f16x8*)(Ah + arow * LP + akp * 8) = hv;
#pragma unroll
        for (int r = 0; r < 4; r++) {
            int f = tid + 256 * r;
            int n = f >> 2, kb = (f & 3) * 8;
            *(f16x8*)(Bh + n * LP + kb) = bv[r];
        }
        __syncthreads();

        // prefetch next chunk (consumed after the MFMA phase)
        if (c + 1 < 16) {
            pa = *(const f16x8*)(Prow + (c + 1) * 32);
            qa = hasQ ? *(const f16x8*)(Qrow + (c + 1) * 32) : zero8;
            const f16* bsrc = W1Bh + (size_t)(c + 1) * (256 * 32);
#pragma unroll
            for (int r = 0; r < 4; r++)
                bv[r] = *(const f16x8*)(bsrc + (size_t)(tid + 256 * r) * 8);
        }

        f16x8 af[4], bf[4];
#pragma unroll
        for (int rt = 0; rt < 4; rt++)
            af[rt] = *(const f16x8*)(Ah + (rt * 16 + l15) * LP + quad * 8);
#pragma unroll
        for (int ct = 0; ct < 4; ct++)
            bf[ct] = *(const f16x8*)(Bh + (wave * 64 + ct * 16 + l15) * LP + quad * 8);
#pragma unroll
        for (int rt = 0; rt < 4; rt++)
#pragma unroll
            for (int ct = 0; ct < 4; ct++)
                acc[rt][ct] = __builtin_amdgcn_mfma_f32_16x16x32_f16(
                    af[rt], bf[ct], acc[rt][ct], 0, 0, 0);
        __syncthreads();
    }

    // epilogue: h = relu(acc + b1); three 256-dots (lk, logit0, logit1)
    float wl[4], wa0[4], wa1[4], bb[4];
#pragma unroll
    for (int ct = 0; ct < 4; ct++) {
        int n = wave * 64 + ct * 16 + l15;
        wl[ct] = Wlk[n];
        wa0[ct] = Wa[2 * n];
        wa1[ct] = Wa[2 * n + 1];
        bb[ct] = b1[n];
    }
#pragma unroll
    for (int rt = 0; rt < 4; rt++) {
#pragma unroll
        for (int reg = 0; reg < 4; reg++) {
            float plk = 0.f, p0 = 0.f, p1 = 0.f;
#pragma unroll
            for (int ct = 0; ct < 4; ct++) {
                float h = fmaxf(acc[rt][ct][reg] + bb[ct], 0.f);
                plk = fmaf(h, wl[ct], plk);
                p0 = fmaf(h, wa0[ct], p0);
                p1 = fmaf(h, wa1[ct], p1);
            }
#pragma unroll
            for (int off = 8; off >= 1; off >>= 1) {
                plk += __shfl_xor(plk, off);
                p0 += __shfl_xor(p0, off);
                p1 += __shfl_xor(p1, off);
            }
            if (l15 == 0) {
                int row = rt * 16 + quad * 4 + reg;
                redA[row][wave] = plk;
                redB[row][wave] = p0;
                redC[row][wave] = p1;
            }
        }
    }
    __syncthreads();
    if (tid < 64) {
        int t = tbase + tid;
        if (t < T_TOT) {
            float lk = redA[tid][0] + redA[tid][1] + redA[tid][2] + redA[tid][3] + blkp[0];
            float l0 = redB[tid][0] + redB[tid][1] + redB[tid][2] + redB[tid][3] + ba[0];
            float l1 = redC[tid][0] + redC[tid][1] + redC[tid][2] + redC[tid][3] + ba[1];
            lk_app[t] = lk;
            logits[2 * t] = l0;
            logits[2 * t + 1] = l1;
            unsigned long long key =
                ((unsigned long long)f2ord(lk) << 32) | (unsigned int)t;
            atomicMax(keys + s_seg[tid], key);
        }
    }
}

// ---------------------------------------------------------------------------
// K_GB: gather (a) challengers within MARGIN_LK of their segment best plus the
// segment's approx winner; (b) approx winners whose logit gap < MARGIN_L.
// Duplicates are harmless (fixup idempotent).
// ---------------------------------------------------------------------------
__global__ void k_gb(const float* __restrict__ lk_app,
                     const unsigned long long* __restrict__ keys,
                     const int* __restrict__ esrc,
                     const float* __restrict__ logits,
                     int* __restrict__ list, int* __restrict__ count) {
    int t = blockIdx.x * 256 + threadIdx.x;
    if (t < T_TOT) {
        int seg = (t < N_EDGES) ? esrc[t] : t - N_EDGES;
        unsigned long long k = keys[seg];
        int tw = (int)(k & 0xFFFFFFFFull);
        if (t != tw) {
            float best = ord2f((unsigned int)(k >> 32));
            if (lk_app[t] >= best - MARGIN_LK) {
                int idx = atomicAdd(count, 2);
                if (idx + 1 < LIST_CAP) { list[idx] = t; list[idx + 1] = tw; }
            }
        }
    }
    if (t < N_NODES) {
        int tw = (int)(keys[t] & 0xFFFFFFFFull);
        float g = fabsf(logits[2 * tw + 1] - logits[2 * tw]);
        if (g < MARGIN_L) {
            int idx = atomicAdd(count, 1);
            if (idx < LIST_CAP) list[idx] = tw;
        }
    }
}

// ---------------------------------------------------------------------------
// K_FIXUP (latency-shaped): ONE BLOCK PER ENTRY. Exact fp32 lk + logits.
// h1 = relu(P[s]+Q[d]) staged in LDS; thread j: dot(h1, W1T[j]) contiguous;
// 3-way block reduction. Tiny LDS/VGPR -> high occupancy, ~350 blocks
// run fully concurrently instead of R5's 0.6%-occupancy throughput tile.
// ---------------------------------------------------------------------------
__global__ __launch_bounds__(256, 4) void k_fixup(
        const float* __restrict__ P, const float* __restrict__ Qm,
        const float* __restrict__ W1T, const float* __restrict__ b1,
        const float* __restrict__ Wlk, const float* __restrict__ blkp,
        const float* __restrict__ Wa, const float* __restrict__ ba,
        const int* __restrict__ esrc, const int* __restrict__ edst,
        const int* __restrict__ list, const int* __restrict__ count,
        unsigned long long* __restrict__ keys2, float* __restrict__ logits) {
    __shared__ float h1[512];
    __shared__ float red[3][4];
    const int tid = threadIdx.x;
    int cnt = *count;
    if (cnt > LIST_CAP) cnt = LIST_CAP;

    // per-thread column constants (uniform across entries)
    const float bb = b1[tid];
    const float wl = Wlk[tid];
    const float w0 = Wa[2 * tid];
    const float w1 = Wa[2 * tid + 1];
    const float* wrow = W1T + (size_t)tid * 512;

    for (int e = blockIdx.x; e < cnt; e += gridDim.x) {
        int t = list[e];                       // block-uniform
        if (t < 0 || t >= T_TOT) continue;     // guard vs poisoned slots
        int s, d;
        if (t < N_EDGES) { s = esrc[t]; d = edst[t]; }
        else { s = t - N_EDGES; d = -1; }

        // stage h1 = relu(P[s] + Q[d])
#pragma unroll
        for (int r = 0; r < 2; r++) {
            int k = tid + 256 * r;
            float v = P[(size_t)s * H0D + k];
            if (d >= 0) v += Qm[(size_t)d * H0D + k];
            h1[k] = fmaxf(v, 0.f);
        }
        __syncthreads();

        // exact column dot: thread j = tid
        float a0 = 0.f, a1 = 0.f, a2 = 0.f, a3 = 0.f;
        for (int k = 0; k < 512; k += 16) {
            float4 wv0 = *(const float4*)(wrow + k);
            float4 wv1 = *(const float4*)(wrow + k + 4);
            float4 wv2 = *(const float4*)(wrow + k + 8);
            float4 wv3 = *(const float4*)(wrow + k + 12);
            float4 hv0 = *(const float4*)(h1 + k);
            float4 hv1 = *(const float4*)(h1 + k + 4);
            float4 hv2 = *(const float4*)(h1 + k + 8);
            float4 hv3 = *(const float4*)(h1 + k + 12);
            a0 = fmaf(hv0.x, wv0.x, a0); a0 = fmaf(hv0.y, wv0.y, a0);
            a0 = fmaf(hv0.z, wv0.z, a0); a0 = fmaf(hv0.w, wv0.w, a0);
            a1 = fmaf(hv1.x, wv1.x, a1); a1 = fmaf(hv1.y, wv1.y, a1);
            a1 = fmaf(hv1.z, wv1.z, a1); a1 = fmaf(hv1.w, wv1.w, a1);
            a2 = fmaf(hv2.x, wv2.x, a2); a2 = fmaf(hv2.y, wv2.y, a2);
            a2 = fmaf(hv2.z, wv2.z, a2); a2 = fmaf(hv2.w, wv2.w, a2);
            a3 = fmaf(hv3.x, wv3.x, a3); a3 = fmaf(hv3.y, wv3.y, a3);
            a3 = fmaf(hv3.z, wv3.z, a3); a3 = fmaf(hv3.w, wv3.w, a3);
        }
        float hj = fmaxf((a0 + a1) + (a2 + a3) + bb, 0.f);
        float plk = hj * wl;
        float p0 = hj * w0;
        float p1 = hj * w1;
#pragma unroll
        for (int off = 32; off >= 1; off >>= 1) {
            plk += __shfl_xor(plk, off);
            p0 += __shfl_xor(p0, off);
            p1 += __shfl_xor(p1, off);
        }
        int wv = tid >> 6;
        if ((tid & 63) == 0) {
            red[0][wv] = plk; red[1][wv] = p0; red[2][wv] = p1;
        }
        __syncthreads();
        if (tid == 0) {
            float lk = red[0][0] + red[0][1] + red[0][2] + red[0][3] + blkp[0];
            float l0 = red[1][0] + red[1][1] + red[1][2] + red[1][3] + ba[0];
            float l1 = red[2][0] + red[2][1] + red[2][2] + red[2][3] + ba[1];
            logits[2 * t] = l0;
            logits[2 * t + 1] = l1;
            unsigned long long key =
                ((unsigned long long)f2ord(lk) << 32) | (unsigned int)t;
            atomicMax(keys2 + s, key);
        }
        __syncthreads();   // protect h1/red before next entry
    }
}

// ---------------------------------------------------------------------------
// K4: winner per node (keys2 if any exact candidates, else approx keys);
// at-bit from logits (exact where at risk); last-writer claim (+1 coded).
// ---------------------------------------------------------------------------
__global__ void k4_select(const unsigned long long* __restrict__ keys,
                          const unsigned long long* __restrict__ keys2,
                          const int* __restrict__ edst,
                          const float* __restrict__ logits,
                          int* __restrict__ chosen_arr,
                          int* __restrict__ tgt_writer) {
    int i = blockIdx.x * 256 + threadIdx.x;
    if (i >= N_NODES) return;
    unsigned long long key = keys[i];
    unsigned long long k2v = keys2[i];
    if (k2v != 0ull) key = k2v;
    int t = (int)(key & 0xFFFFFFFFull);
    int chosen = (t < N_EDGES) ? edst[t] : -1;
    float lg0 = logits[2 * t], lg1 = logits[2 * t + 1];
    int at1 = (lg1 > lg0) ? 1 : 0;   // argmax: tie -> index 0
    int c = (chosen >= 0 && at1) ? chosen : -1;
    chosen_arr[i] = c;
    if (c >= 0) atomicMax(tgt_writer + c, i + 1);   // last-write-wins: max i
}

// ---------------------------------------------------------------------------
// K5: winning writers update rows: out[c] = relu(0.5*(Z[i] + Z[c]))
// ---------------------------------------------------------------------------
__global__ void k5_update(const int* __restrict__ chosen_arr,
                          const int* __restrict__ tgt_writer,
                          const float* __restrict__ Z,
                          float* __restrict__ out) {
    int i = blockIdx.x;
    int c = chosen_arr[i];
    if (c < 0 || tgt_writer[c] != i + 1) return;
    int n = threadIdx.x;
    float z = 0.5f * (Z[(size_t)i * E_DIM + n] + Z[(size_t)c * E_DIM + n]);
    out[(size_t)c * E_DIM + n] = fmaxf(z, 0.f);
}

// ---------------------------------------------------------------------------
extern "C" void kernel_launch(void* const* d_in, const int* in_sizes, int n_in,
                              void* d_out, int out_size, void* d_ws,
                              size_t ws_size, hipStream_t stream) {
    const float* feat = (const float*)d_in[0];
    const float* We   = (const float*)d_in[1];
    const float* be   = (const float*)d_in[2];
    const float* W0   = (const float*)d_in[3];
    const float* b0   = (const float*)d_in[4];
    const float* W1   = (const float*)d_in[5];
    const float* b1   = (const float*)d_in[6];
    const float* Wlk  = (const float*)d_in[7];
    const float* blkp = (const float*)d_in[8];
    const float* Wa   = (const float*)d_in[9];
    const float* ba   = (const float*)d_in[10];
    const int* esrc   = (const int*)d_in[11];
    const int* edst   = (const int*)d_in[12];
    float* out = (float*)d_out;

    char* ws = (char*)d_ws;
    size_t off = 0;
    float* Z  = (float*)(ws + off); off += (size_t)N_NODES * E_DIM * 4;
    float* P  = (float*)(ws + off); off += (size_t)N_NODES * H0D * 4;
    float* Qm = (float*)(ws + off); off += (size_t)N_NODES * H0D * 4;
    f16* Pf   = (f16*)(ws + off);   off += (size_t)N_NODES * H0D * 2;
    f16* Qf   = (f16*)(ws + off);   off += (size_t)N_NODES * H0D * 2;
    // ---- contiguous zero-init region ----
    char* zero_base = ws + off;
    unsigned long long* keys  = (unsigned long long*)(ws + off); off += N_NODES * 8;
    unsigned long long* keys2 = (unsigned long long*)(ws + off); off += N_NODES * 8;
    int* tgt_writer = (int*)(ws + off); off += N_NODES * 4;   // +1 encoding, 0 = none
    int* count      = (int*)(ws + off); off += 128;
    size_t zero_bytes = (size_t)((ws + off) - zero_base);
    // -------------------------------------
    float* logits = (float*)(ws + off); off += (size_t)T_TOT * 2 * 4;
    float* lk_app = (float*)(ws + off); off += (size_t)T_TOT * 4;
    int* list     = (int*)(ws + off); off += (size_t)LIST_CAP * 4;
    int* chosen_arr = (int*)(ws + off); off += N_NODES * 4;
    f16* WeC_h = (f16*)(ws + off); off += (size_t)16 * 256 * 32 * 2;
    f16* WeC_l = (f16*)(ws + off); off += (size_t)16 * 256 * 32 * 2;
    f16* W1C_h = (f16*)(ws + off); off += (size_t)16 * 256 * 32 * 2;
    f16* W1C_l = (f16*)(ws + off); off += (size_t)16 * 256 * 32 * 2;
    f16* W0C_h = (f16*)(ws + off); off += (size_t)32 * 256 * 32 * 2;
    f16* W0C_l = (f16*)(ws + off); off += (size_t)32 * 256 * 32 * 2;
    float* W1T = (float*)(ws + off); off += (size_t)H1D * H0D * 4;   // 512 KB

    hipMemsetAsync(zero_base, 0, zero_bytes, stream);

    k_prep_all<<<dim3(96), 256, 0, stream>>>(
        We, W1, W0, WeC_h, WeC_l, W1C_h, W1C_l, W0C_h, W0C_l, W1T);
    k1_split<<<dim3((N_NODES + 63) / 64), 256, 0, stream>>>(
        feat, WeC_h, WeC_l, be, Z, out);
    k2_split<<<dim3((N_NODES + 63) / 64, 4), 256, 0, stream>>>(
        out, W0C_h, W0C_l, b0, P, Qm, Pf, Qf);
    k3_f16<<<dim3((T_TOT + 63) / 64), 256, 0, stream>>>(
        Pf, Qf, W1C_h, b1, Wlk, blkp, Wa, ba, esrc, edst,
        keys, lk_app, logits);
    k_gb<<<dim3((T_TOT + 255) / 256), 256, 0, stream>>>(
        lk_app, keys, esrc, logits, list, count);
    k_fixup<<<dim3(FIX_GRID), 256, 0, stream>>>(
        P, Qm, W1T, b1, Wlk, blkp, Wa, ba, esrc, edst, list, count, keys2, logits);
    k4_select<<<dim3((N_NODES + 255) / 256), 256, 0, stream>>>(
        keys, keys2, edst, logits, chosen_arr, tgt_writer);
    k5_update<<<dim3(N_NODES), 256, 0, stream>>>(chosen_arr, tgt_writer, Z, out);
}